// Round 2
// baseline (516.105 us; speedup 1.0000x reference)
//
#include <hip/hip_runtime.h>
#include <hip/hip_bf16.h>

typedef __attribute__((ext_vector_type(4))) float f32x4;
typedef __attribute__((ext_vector_type(8))) short s16x8;
typedef __attribute__((ext_vector_type(4))) short s16x4;

// ---------------- RoPE tables (tiny, double precision) ----------------
__global__ void rope_tables(float* __restrict__ cosT, float* __restrict__ sinT) {
    const int s = blockIdx.x, j = threadIdx.x;          // s in [0,2048), j in [0,64)
    const double inv = pow(10000.0, -(double)j / 64.0);
    const double f = (double)s * inv;
    cosT[s * 64 + j] = (float)cos(f);
    sinT[s * 64 + j] = (float)sin(f);
}

// ---------------- cast fp32 -> bf16 (vectorized) ----------------
__global__ __launch_bounds__(256)
void cast_f32_bf16(const float* __restrict__ src, __hip_bfloat16* __restrict__ dst, int n4) {
    const int i = blockIdx.x * 256 + threadIdx.x;
    if (i < n4) {
        f32x4 v = *reinterpret_cast<const f32x4*>(src + (size_t)i * 4);
        union { s16x4 v4; __hip_bfloat16 h[4]; } u;
#pragma unroll
        for (int j = 0; j < 4; ++j) u.h[j] = __float2bfloat16(v[j]);
        *reinterpret_cast<s16x4*>(dst + (size_t)i * 4) = u.v4;
    }
}

// ---------------- tiled transpose + cast: dst[c][r] = (bf16)src[r][c] ----------------
__global__ __launch_bounds__(256)
void transpose_cast(const float* __restrict__ src, __hip_bfloat16* __restrict__ dst,
                    int R, int C) {
    __shared__ __align__(16) float t[32][33];
    const int tx = threadIdx.x, ty = threadIdx.y;       // (32, 8)
    const int r0 = blockIdx.y * 32, c0 = blockIdx.x * 32;
#pragma unroll
    for (int i = 0; i < 32; i += 8)
        t[ty + i][tx] = src[(size_t)(r0 + ty + i) * C + c0 + tx];
    __syncthreads();
#pragma unroll
    for (int i = 0; i < 32; i += 8)
        dst[(size_t)(c0 + ty + i) * R + r0 + tx] = __float2bfloat16(t[tx][ty + i]);
}

// ---------------- m97-style bf16 GEMM: C(f32)[M][N] = A[M][K] * Bt[N][K]^T ----------------
__global__ __launch_bounds__(256)
void gemm_bt_f32(const __hip_bfloat16* __restrict__ A,
                 const __hip_bfloat16* __restrict__ Bt,
                 float* __restrict__ C, int M, int N, int K) {
    __shared__ __align__(16) __hip_bfloat16 As[128 * 32];
    __shared__ __align__(16) __hip_bfloat16 Bs[128 * 32];
    const int tid = threadIdx.x;
    const int l = tid & 63, w = tid >> 6;
    const int row0 = blockIdx.y * 128, col0 = blockIdx.x * 128;
    const int wr = (w >> 1) * 64, wc = (w & 1) * 64;   // wave's 64x64 sub-tile
    f32x4 acc[4][4] = {};
    const int nk = K >> 5;
    for (int ks = 0; ks < nk; ++ks) {
        const int k0 = ks << 5;
#pragma unroll
        for (int i = 0; i < 2; ++i) {
            const int c = i * 256 + tid;               // 16B chunk id, 0..511
            const int r = c >> 2, cc = (c & 3) * 8;    // 4 chunks per 32-col row
            __builtin_amdgcn_global_load_lds(
                (const __attribute__((address_space(1))) void*)(A + (size_t)(row0 + r) * K + k0 + cc),
                (__attribute__((address_space(3))) void*)(As + c * 8), 16, 0, 0);
            __builtin_amdgcn_global_load_lds(
                (const __attribute__((address_space(1))) void*)(Bt + (size_t)(col0 + r) * K + k0 + cc),
                (__attribute__((address_space(3))) void*)(Bs + c * 8), 16, 0, 0);
        }
        __syncthreads();
        s16x8 af[4], bf[4];
#pragma unroll
        for (int mi = 0; mi < 4; ++mi)
            af[mi] = *reinterpret_cast<const s16x8*>(As + (wr + mi * 16 + (l & 15)) * 32 + (l >> 4) * 8);
#pragma unroll
        for (int ni = 0; ni < 4; ++ni)
            bf[ni] = *reinterpret_cast<const s16x8*>(Bs + (wc + ni * 16 + (l & 15)) * 32 + (l >> 4) * 8);
#pragma unroll
        for (int mi = 0; mi < 4; ++mi)
#pragma unroll
            for (int ni = 0; ni < 4; ++ni)
                acc[mi][ni] = __builtin_amdgcn_mfma_f32_16x16x32_bf16(af[mi], bf[ni], acc[mi][ni], 0, 0, 0);
        __syncthreads();
    }
    const int rbase = row0 + wr + ((l >> 4) * 4);
    const int cbase = col0 + wc + (l & 15);
#pragma unroll
    for (int mi = 0; mi < 4; ++mi)
#pragma unroll
        for (int ni = 0; ni < 4; ++ni)
#pragma unroll
            for (int r = 0; r < 4; ++r)
                C[(size_t)(rbase + mi * 16 + r) * N + cbase + ni * 16] = acc[mi][ni][r];
}

// ---------------- RoPE + scatter into attention layouts ----------------
// qkv: f32 [4096][3072] (Q 0..2047 | K 2048..2559 | V 2560..3071)
// Qr: bf16 [2][16][2048][128], Kr: bf16 [2][4][2048][128], Vt: bf16 [2][4][128][2048]
__global__ __launch_bounds__(256)
void rope_scatter(const float* __restrict__ qkv,
                  const float* __restrict__ cosT, const float* __restrict__ sinT,
                  __hip_bfloat16* __restrict__ Qr, __hip_bfloat16* __restrict__ Kr,
                  __hip_bfloat16* __restrict__ Vt) {
    const int m = blockIdx.y;                           // token row, 0..4095
    const int col = blockIdx.x * 256 + threadIdx.x;     // 0..3071
    const int b = m >> 11, s = m & 2047;
    const float v = qkv[(size_t)m * 3072 + col];
    if (col < 2560) {                                   // Q or K: apply RoPE
        const int d = col & 127;                        // head-aligned regions
        const int j = d & 63;
        const float c = cosT[s * 64 + j], sn = sinT[s * 64 + j];
        const float partner = qkv[(size_t)m * 3072 + (col ^ 64)];
        const float rot = (d < 64) ? -partner : partner;
        const float o = v * c + rot * sn;
        if (col < 2048) {
            const int hh = col >> 7;
            Qr[((size_t)(b * 16 + hh) * 2048 + s) * 128 + d] = __float2bfloat16(o);
        } else {
            const int hh = (col - 2048) >> 7;
            Kr[((size_t)(b * 4 + hh) * 2048 + s) * 128 + d] = __float2bfloat16(o);
        }
    } else {                                            // V: transpose-scatter
        const int cc = col - 2560;
        const int hh = cc >> 7, d = cc & 127;
        Vt[((size_t)(b * 4 + hh) * 128 + d) * 2048 + s] = __float2bfloat16(v);
    }
}

// ---------------- flash attention: 64 Q-rows/block, KV tiles of 64 ----------------
__global__ __launch_bounds__(256)
void attn_kernel(const __hip_bfloat16* __restrict__ Qr,
                 const __hip_bfloat16* __restrict__ Kr,
                 const __hip_bfloat16* __restrict__ Vt,
                 const int* __restrict__ mask,
                 __hip_bfloat16* __restrict__ Oo) {
    const int S = 2048;
    const int qt = blockIdx.x;                          // 0..31
    const int bh = blockIdx.y;                          // 0..31
    const int b = bh >> 4, h = bh & 15, kvh = h >> 2;
    const int l = threadIdx.x & 63, w = threadIdx.x >> 6;
    __shared__ __align__(16) __hip_bfloat16 Ks[64 * 136];   // [64][128+8]
    __shared__ __align__(16) __hip_bfloat16 Vs[128 * 72];   // [128][64+8]
    __shared__ __align__(16) __hip_bfloat16 Ps[4][16 * 72]; // per-wave P [16][64+8]

    const __hip_bfloat16* Qb = Qr + (size_t)(b * 16 + h) * S * 128;
    const __hip_bfloat16* Kb = Kr + (size_t)(b * 4 + kvh) * S * 128;
    const __hip_bfloat16* Vb = Vt + (size_t)(b * 4 + kvh) * 128 * S;

    // Q fragments held in registers: wave owns rows qt*64 + w*16 .. +15
    const int qrow = qt * 64 + w * 16 + (l & 15);
    s16x8 qf[4];
#pragma unroll
    for (int kc = 0; kc < 4; ++kc)
        qf[kc] = *reinterpret_cast<const s16x8*>(Qb + (size_t)qrow * 128 + kc * 32 + (l >> 4) * 8);

    float m_run[4], l_run[4];
    f32x4 o[8];
#pragma unroll
    for (int r = 0; r < 4; ++r) { m_run[r] = -1e30f; l_run[r] = 0.f; }
#pragma unroll
    for (int n = 0; n < 8; ++n) o[n] = f32x4{0.f, 0.f, 0.f, 0.f};
    const float scale = 0.08838834764831845f;           // 1/sqrt(128)

    for (int kt = 0; kt < 32; ++kt) {
        const int kv0 = kt * 64;
#pragma unroll
        for (int i = 0; i < 4; ++i) {                   // K tile: 64 rows x 128 cols
            const int c = i * 256 + threadIdx.x;        // chunk id, 0..1023
            const int r = c >> 4, cc = (c & 15) * 8;    // FIX: 16 chunks per 128-col row
            *reinterpret_cast<s16x8*>(Ks + r * 136 + cc) =
                *reinterpret_cast<const s16x8*>(Kb + (size_t)(kv0 + r) * 128 + cc);
        }
#pragma unroll
        for (int i = 0; i < 4; ++i) {                   // V^T tile: 128 rows x 64 cols
            const int c = i * 256 + threadIdx.x;
            const int d = c >> 3, cc = (c & 7) * 8;     // 8 chunks per 64-col row
            *reinterpret_cast<s16x8*>(Vs + d * 72 + cc) =
                *reinterpret_cast<const s16x8*>(Vb + (size_t)d * S + kv0 + cc);
        }
        __syncthreads();

        // S = Q K^T  (rows q = (l>>4)*4+r, col key = ksub*16 + (l&15))
        f32x4 sc[4] = {};
#pragma unroll
        for (int ksub = 0; ksub < 4; ++ksub)
#pragma unroll
            for (int kc = 0; kc < 4; ++kc) {
                s16x8 kf = *reinterpret_cast<const s16x8*>(
                    Ks + (ksub * 16 + (l & 15)) * 136 + kc * 32 + (l >> 4) * 8);
                sc[ksub] = __builtin_amdgcn_mfma_f32_16x16x32_bf16(qf[kc], kf, sc[ksub], 0, 0, 0);
            }
        // mask + scale
#pragma unroll
        for (int ksub = 0; ksub < 4; ++ksub) {
            const float bias = (mask[b * S + kv0 + ksub * 16 + (l & 15)] == 0) ? -1e30f : 0.f;
#pragma unroll
            for (int r = 0; r < 4; ++r) sc[ksub][r] = sc[ksub][r] * scale + bias;
        }
        // online softmax (row reductions across the 16-lane group)
        float alpha[4];
#pragma unroll
        for (int r = 0; r < 4; ++r) {
            float v = fmaxf(fmaxf(sc[0][r], sc[1][r]), fmaxf(sc[2][r], sc[3][r]));
#pragma unroll
            for (int off = 1; off < 16; off <<= 1) v = fmaxf(v, __shfl_xor(v, off));
            const float mnew = fmaxf(m_run[r], v);
            alpha[r] = __expf(m_run[r] - mnew);
            m_run[r] = mnew;
        }
#pragma unroll
        for (int r = 0; r < 4; ++r) {
            float s = 0.f;
#pragma unroll
            for (int ksub = 0; ksub < 4; ++ksub) {
                const float p = __expf(sc[ksub][r] - m_run[r]);
                sc[ksub][r] = p;
                s += p;
            }
#pragma unroll
            for (int off = 1; off < 16; off <<= 1) s += __shfl_xor(s, off);
            l_run[r] = l_run[r] * alpha[r] + s;
        }
#pragma unroll
        for (int n = 0; n < 8; ++n)
#pragma unroll
            for (int r = 0; r < 4; ++r) o[n][r] *= alpha[r];
        // P -> LDS (bf16), reshaped to PV A-fragment layout
        __hip_bfloat16* pb = &Ps[w][0];
#pragma unroll
        for (int ksub = 0; ksub < 4; ++ksub)
#pragma unroll
            for (int r = 0; r < 4; ++r)
                pb[((l >> 4) * 4 + r) * 72 + ksub * 16 + (l & 15)] = __float2bfloat16(sc[ksub][r]);
        // O += P V
#pragma unroll
        for (int kg = 0; kg < 2; ++kg) {
            s16x8 pa = *reinterpret_cast<const s16x8*>(pb + (l & 15) * 72 + kg * 32 + (l >> 4) * 8);
#pragma unroll
            for (int n = 0; n < 8; ++n) {
                s16x8 vb = *reinterpret_cast<const s16x8*>(
                    Vs + (n * 16 + (l & 15)) * 72 + kg * 32 + (l >> 4) * 8);
                o[n] = __builtin_amdgcn_mfma_f32_16x16x32_bf16(pa, vb, o[n], 0, 0, 0);
            }
        }
        __syncthreads();
    }
    // epilogue: attn_out[b*S+s][h*128+d] = o / l
    const int orow = b * S + qt * 64 + w * 16 + ((l >> 4) * 4);
    const int ocol = h * 128 + (l & 15);
#pragma unroll
    for (int n = 0; n < 8; ++n)
#pragma unroll
        for (int r = 0; r < 4; ++r)
            Oo[(size_t)(orow + r) * 2048 + ocol + n * 16] = __float2bfloat16(o[n][r] / l_run[r]);
}

// ---------------- host launch ----------------
extern "C" void kernel_launch(void* const* d_in, const int* in_sizes, int n_in,
                              void* d_out, int out_size, void* d_ws, size_t ws_size,
                              hipStream_t stream) {
    const float* x  = (const float*)d_in[0];
    const int* mask = (const int*)d_in[1];
    const float* Wq = (const float*)d_in[2];
    const float* Wk = (const float*)d_in[3];
    const float* Wv = (const float*)d_in[4];
    const float* Wo = (const float*)d_in[5];
    float* out = (float*)d_out;

    char* ws = (char*)d_ws;
    size_t off = 0;
    auto alloc = [&](size_t bytes) -> void* {
        void* p = ws + off;
        off += (bytes + 255) & ~(size_t)255;
        return p;
    };
    // Distinct regions (~93 MB peak):
    __hip_bfloat16* xb     = (__hip_bfloat16*)alloc(4096ULL * 2048 * 2);   // 16 MB
    __hip_bfloat16* wqkv_t = (__hip_bfloat16*)alloc(3072ULL * 2048 * 2);   // 12 MB
    __hip_bfloat16* wo_t   = (__hip_bfloat16*)alloc(2048ULL * 2048 * 2);   // 8 MB
    float*          qkv    = (float*)alloc(4096ULL * 3072 * 4);            // 48 MB
    __hip_bfloat16* Kr     = (__hip_bfloat16*)alloc(2ULL * 4 * 2048 * 128 * 2);  // 4 MB
    __hip_bfloat16* Vt     = (__hip_bfloat16*)alloc(2ULL * 4 * 2048 * 128 * 2);  // 4 MB
    float*          cosT   = (float*)alloc(2048ULL * 64 * 4);
    float*          sinT   = (float*)alloc(2048ULL * 64 * 4);
    // Aliases (regions dead by the time these are written):
    __hip_bfloat16* Qr    = xb;                   // xb dead after QKV GEMM; Qr written after
    __hip_bfloat16* attno = (__hip_bfloat16*)qkv; // qkv dead after rope_scatter; attno written after

    rope_tables<<<dim3(2048), dim3(64), 0, stream>>>(cosT, sinT);
    cast_f32_bf16<<<dim3(8192), dim3(256), 0, stream>>>(x, xb, 2097152);
    transpose_cast<<<dim3(64, 64), dim3(32, 8), 0, stream>>>(Wq, wqkv_t, 2048, 2048);
    transpose_cast<<<dim3(16, 64), dim3(32, 8), 0, stream>>>(Wk, wqkv_t + 2048ULL * 2048, 2048, 512);
    transpose_cast<<<dim3(16, 64), dim3(32, 8), 0, stream>>>(Wv, wqkv_t + 2560ULL * 2048, 2048, 512);
    transpose_cast<<<dim3(64, 64), dim3(32, 8), 0, stream>>>(Wo, wo_t, 2048, 2048);

    gemm_bt_f32<<<dim3(24, 32), dim3(256), 0, stream>>>(xb, wqkv_t, qkv, 4096, 3072, 2048);
    rope_scatter<<<dim3(12, 4096), dim3(256), 0, stream>>>(qkv, cosT, sinT, Qr, Kr, Vt);
    attn_kernel<<<dim3(32, 32), dim3(256), 0, stream>>>(Qr, Kr, Vt, mask, attno);
    gemm_bt_f32<<<dim3(16, 32), dim3(256), 0, stream>>>(attno, wo_t, out, 4096, 2048, 2048);
}

// Round 3
// 512.923 us; speedup vs baseline: 1.0062x; 1.0062x over previous
//
#include <hip/hip_runtime.h>
#include <hip/hip_bf16.h>

typedef __attribute__((ext_vector_type(4))) float f32x4;
typedef __attribute__((ext_vector_type(8))) short s16x8;
typedef __attribute__((ext_vector_type(4))) short s16x4;

// ---------------- RoPE tables (tiny, double precision) ----------------
__global__ void rope_tables(float* __restrict__ cosT, float* __restrict__ sinT) {
    const int s = blockIdx.x, j = threadIdx.x;          // s in [0,2048), j in [0,64)
    const double inv = pow(10000.0, -(double)j / 64.0);
    const double f = (double)s * inv;
    cosT[s * 64 + j] = (float)cos(f);
    sinT[s * 64 + j] = (float)sin(f);
}

// ---------------- cast fp32 -> bf16 (vectorized) ----------------
__global__ __launch_bounds__(256)
void cast_f32_bf16(const float* __restrict__ src, __hip_bfloat16* __restrict__ dst, int n4) {
    const int i = blockIdx.x * 256 + threadIdx.x;
    if (i < n4) {
        f32x4 v = *reinterpret_cast<const f32x4*>(src + (size_t)i * 4);
        union { s16x4 v4; __hip_bfloat16 h[4]; } u;
#pragma unroll
        for (int j = 0; j < 4; ++j) u.h[j] = __float2bfloat16(v[j]);
        *reinterpret_cast<s16x4*>(dst + (size_t)i * 4) = u.v4;
    }
}

// ---------------- tiled transpose + cast: dst[c][r] = (bf16)src[r][c] ----------------
__global__ __launch_bounds__(256)
void transpose_cast(const float* __restrict__ src, __hip_bfloat16* __restrict__ dst,
                    int R, int C) {
    __shared__ __align__(16) float t[32][33];
    const int tx = threadIdx.x, ty = threadIdx.y;       // (32, 8)
    const int r0 = blockIdx.y * 32, c0 = blockIdx.x * 32;
#pragma unroll
    for (int i = 0; i < 32; i += 8)
        t[ty + i][tx] = src[(size_t)(r0 + ty + i) * C + c0 + tx];
    __syncthreads();
#pragma unroll
    for (int i = 0; i < 32; i += 8)
        dst[(size_t)(c0 + ty + i) * R + r0 + tx] = __float2bfloat16(t[tx][ty + i]);
}

// ---------------- m97-style bf16 GEMM: C(f32)[M][N] = A[M][K] * Bt[N][K]^T ----------------
__global__ __launch_bounds__(256)
void gemm_bt_f32(const __hip_bfloat16* __restrict__ A,
                 const __hip_bfloat16* __restrict__ Bt,
                 float* __restrict__ C, int M, int N, int K) {
    __shared__ __align__(16) __hip_bfloat16 As[128 * 32];
    __shared__ __align__(16) __hip_bfloat16 Bs[128 * 32];
    const int tid = threadIdx.x;
    const int l = tid & 63, w = tid >> 6;
    const int row0 = blockIdx.y * 128, col0 = blockIdx.x * 128;
    const int wr = (w >> 1) * 64, wc = (w & 1) * 64;   // wave's 64x64 sub-tile
    f32x4 acc[4][4] = {};
    const int nk = K >> 5;
    for (int ks = 0; ks < nk; ++ks) {
        const int k0 = ks << 5;
#pragma unroll
        for (int i = 0; i < 2; ++i) {
            const int c = i * 256 + tid;               // 16B chunk id, 0..511
            const int r = c >> 2, cc = (c & 3) * 8;    // 4 chunks per 32-col row
            __builtin_amdgcn_global_load_lds(
                (const __attribute__((address_space(1))) void*)(A + (size_t)(row0 + r) * K + k0 + cc),
                (__attribute__((address_space(3))) void*)(As + c * 8), 16, 0, 0);
            __builtin_amdgcn_global_load_lds(
                (const __attribute__((address_space(1))) void*)(Bt + (size_t)(col0 + r) * K + k0 + cc),
                (__attribute__((address_space(3))) void*)(Bs + c * 8), 16, 0, 0);
        }
        __syncthreads();
        s16x8 af[4], bf[4];
#pragma unroll
        for (int mi = 0; mi < 4; ++mi)
            af[mi] = *reinterpret_cast<const s16x8*>(As + (wr + mi * 16 + (l & 15)) * 32 + (l >> 4) * 8);
#pragma unroll
        for (int ni = 0; ni < 4; ++ni)
            bf[ni] = *reinterpret_cast<const s16x8*>(Bs + (wc + ni * 16 + (l & 15)) * 32 + (l >> 4) * 8);
#pragma unroll
        for (int mi = 0; mi < 4; ++mi)
#pragma unroll
            for (int ni = 0; ni < 4; ++ni)
                acc[mi][ni] = __builtin_amdgcn_mfma_f32_16x16x32_bf16(af[mi], bf[ni], acc[mi][ni], 0, 0, 0);
        __syncthreads();
    }
    const int rbase = row0 + wr + ((l >> 4) * 4);
    const int cbase = col0 + wc + (l & 15);
#pragma unroll
    for (int mi = 0; mi < 4; ++mi)
#pragma unroll
        for (int ni = 0; ni < 4; ++ni)
#pragma unroll
            for (int r = 0; r < 4; ++r)
                C[(size_t)(rbase + mi * 16 + r) * N + cbase + ni * 16] = acc[mi][ni][r];
}

// ---------------- RoPE + scatter into attention layouts ----------------
// qkv: f32 [4096][3072] (Q 0..2047 | K 2048..2559 | V 2560..3071)
// Qr: bf16 [2][16][2048][128], Kr: bf16 [2][4][2048][128], Vt: bf16 [2][4][128][2048]
__global__ __launch_bounds__(256)
void rope_scatter(const float* __restrict__ qkv,
                  const float* __restrict__ cosT, const float* __restrict__ sinT,
                  __hip_bfloat16* __restrict__ Qr, __hip_bfloat16* __restrict__ Kr,
                  __hip_bfloat16* __restrict__ Vt) {
    const int m = blockIdx.y;                           // token row, 0..4095
    const int col = blockIdx.x * 256 + threadIdx.x;     // 0..3071
    const int b = m >> 11, s = m & 2047;
    const float v = qkv[(size_t)m * 3072 + col];
    if (col < 2560) {                                   // Q or K: apply RoPE
        const int d = col & 127;                        // head-aligned regions
        const int j = d & 63;
        const float c = cosT[s * 64 + j], sn = sinT[s * 64 + j];
        const float partner = qkv[(size_t)m * 3072 + (col ^ 64)];
        const float rot = (d < 64) ? -partner : partner;
        const float o = v * c + rot * sn;
        if (col < 2048) {
            const int hh = col >> 7;
            Qr[((size_t)(b * 16 + hh) * 2048 + s) * 128 + d] = __float2bfloat16(o);
        } else {
            const int hh = (col - 2048) >> 7;
            Kr[((size_t)(b * 4 + hh) * 2048 + s) * 128 + d] = __float2bfloat16(o);
        }
    } else {                                            // V: transpose-scatter
        const int cc = col - 2560;
        const int hh = cc >> 7, d = cc & 127;
        Vt[((size_t)(b * 4 + hh) * 128 + d) * 2048 + s] = __float2bfloat16(v);
    }
}

// ---------------- flash attention: 64 Q-rows/block, KV tiles of 64 ----------------
__global__ __launch_bounds__(256)
void attn_kernel(const __hip_bfloat16* __restrict__ Qr,
                 const __hip_bfloat16* __restrict__ Kr,
                 const __hip_bfloat16* __restrict__ Vt,
                 const int* __restrict__ mask,
                 __hip_bfloat16* __restrict__ Oo) {
    const int S = 2048;
    const int qt = blockIdx.x;                          // 0..31
    const int bh = blockIdx.y;                          // 0..31
    const int b = bh >> 4, h = bh & 15, kvh = h >> 2;
    const int l = threadIdx.x & 63, w = threadIdx.x >> 6;
    __shared__ __align__(16) __hip_bfloat16 Ks[64 * 136];   // [64][128+8]
    __shared__ __align__(16) __hip_bfloat16 Vs[128 * 72];   // [128][64+8]
    __shared__ __align__(16) __hip_bfloat16 Ps[4][16 * 72]; // per-wave P [16][64+8]

    const __hip_bfloat16* Qb = Qr + (size_t)(b * 16 + h) * S * 128;
    const __hip_bfloat16* Kb = Kr + (size_t)(b * 4 + kvh) * S * 128;
    const __hip_bfloat16* Vb = Vt + (size_t)(b * 4 + kvh) * 128 * S;

    // Q fragments held in registers: wave owns rows qt*64 + w*16 .. +15
    const int qrow = qt * 64 + w * 16 + (l & 15);
    s16x8 qf[4];
#pragma unroll
    for (int kc = 0; kc < 4; ++kc)
        qf[kc] = *reinterpret_cast<const s16x8*>(Qb + (size_t)qrow * 128 + kc * 32 + (l >> 4) * 8);

    float m_run[4], l_run[4];
    f32x4 o[8];
#pragma unroll
    for (int r = 0; r < 4; ++r) { m_run[r] = -1e30f; l_run[r] = 0.f; }
#pragma unroll
    for (int n = 0; n < 8; ++n) o[n] = f32x4{0.f, 0.f, 0.f, 0.f};
    const float scale = 0.08838834764831845f;           // 1/sqrt(128)

    for (int kt = 0; kt < 32; ++kt) {
        const int kv0 = kt * 64;
#pragma unroll
        for (int i = 0; i < 4; ++i) {                   // K tile: 64 rows x 128 cols
            const int c = i * 256 + threadIdx.x;        // chunk id, 0..1023
            const int r = c >> 4, cc = (c & 15) * 8;    // FIX: 16 chunks per 128-col row
            *reinterpret_cast<s16x8*>(Ks + r * 136 + cc) =
                *reinterpret_cast<const s16x8*>(Kb + (size_t)(kv0 + r) * 128 + cc);
        }
#pragma unroll
        for (int i = 0; i < 4; ++i) {                   // V^T tile: 128 rows x 64 cols
            const int c = i * 256 + threadIdx.x;
            const int d = c >> 3, cc = (c & 7) * 8;     // 8 chunks per 64-col row
            *reinterpret_cast<s16x8*>(Vs + d * 72 + cc) =
                *reinterpret_cast<const s16x8*>(Vb + (size_t)d * S + kv0 + cc);
        }
        __syncthreads();

        // S = Q K^T  (rows q = (l>>4)*4+r, col key = ksub*16 + (l&15))
        f32x4 sc[4] = {};
#pragma unroll
        for (int ksub = 0; ksub < 4; ++ksub)
#pragma unroll
            for (int kc = 0; kc < 4; ++kc) {
                s16x8 kf = *reinterpret_cast<const s16x8*>(
                    Ks + (ksub * 16 + (l & 15)) * 136 + kc * 32 + (l >> 4) * 8);
                sc[ksub] = __builtin_amdgcn_mfma_f32_16x16x32_bf16(qf[kc], kf, sc[ksub], 0, 0, 0);
            }
        // mask + scale
#pragma unroll
        for (int ksub = 0; ksub < 4; ++ksub) {
            const float bias = (mask[b * S + kv0 + ksub * 16 + (l & 15)] == 0) ? -1e30f : 0.f;
#pragma unroll
            for (int r = 0; r < 4; ++r) sc[ksub][r] = sc[ksub][r] * scale + bias;
        }
        // online softmax (row reductions across the 16-lane group)
        float alpha[4];
#pragma unroll
        for (int r = 0; r < 4; ++r) {
            float v = fmaxf(fmaxf(sc[0][r], sc[1][r]), fmaxf(sc[2][r], sc[3][r]));
#pragma unroll
            for (int off = 1; off < 16; off <<= 1) v = fmaxf(v, __shfl_xor(v, off));
            const float mnew = fmaxf(m_run[r], v);
            alpha[r] = __expf(m_run[r] - mnew);
            m_run[r] = mnew;
        }
#pragma unroll
        for (int r = 0; r < 4; ++r) {
            float s = 0.f;
#pragma unroll
            for (int ksub = 0; ksub < 4; ++ksub) {
                const float p = __expf(sc[ksub][r] - m_run[r]);
                sc[ksub][r] = p;
                s += p;
            }
#pragma unroll
            for (int off = 1; off < 16; off <<= 1) s += __shfl_xor(s, off);
            l_run[r] = l_run[r] * alpha[r] + s;
        }
#pragma unroll
        for (int n = 0; n < 8; ++n)
#pragma unroll
            for (int r = 0; r < 4; ++r) o[n][r] *= alpha[r];
        // P -> LDS (bf16), reshaped to PV A-fragment layout
        __hip_bfloat16* pb = &Ps[w][0];
#pragma unroll
        for (int ksub = 0; ksub < 4; ++ksub)
#pragma unroll
            for (int r = 0; r < 4; ++r)
                pb[((l >> 4) * 4 + r) * 72 + ksub * 16 + (l & 15)] = __float2bfloat16(sc[ksub][r]);
        // O += P V
#pragma unroll
        for (int kg = 0; kg < 2; ++kg) {
            s16x8 pa = *reinterpret_cast<const s16x8*>(pb + (l & 15) * 72 + kg * 32 + (l >> 4) * 8);
#pragma unroll
            for (int n = 0; n < 8; ++n) {
                s16x8 vb = *reinterpret_cast<const s16x8*>(
                    Vs + (n * 16 + (l & 15)) * 72 + kg * 32 + (l >> 4) * 8);
                o[n] = __builtin_amdgcn_mfma_f32_16x16x32_bf16(pa, vb, o[n], 0, 0, 0);
            }
        }
        __syncthreads();
    }
    // epilogue: attn_out[b*S+s][h*128+d] = o / l
    const int orow = b * S + qt * 64 + w * 16 + ((l >> 4) * 4);
    const int ocol = h * 128 + (l & 15);
#pragma unroll
    for (int n = 0; n < 8; ++n)
#pragma unroll
        for (int r = 0; r < 4; ++r)
            Oo[(size_t)(orow + r) * 2048 + ocol + n * 16] = __float2bfloat16(o[n][r] / l_run[r]);
}

// ---------------- host launch ----------------
extern "C" void kernel_launch(void* const* d_in, const int* in_sizes, int n_in,
                              void* d_out, int out_size, void* d_ws, size_t ws_size,
                              hipStream_t stream) {
    const float* x  = (const float*)d_in[0];
    const int* mask = (const int*)d_in[1];
    const float* Wq = (const float*)d_in[2];
    const float* Wk = (const float*)d_in[3];
    const float* Wv = (const float*)d_in[4];
    const float* Wo = (const float*)d_in[5];
    float* out = (float*)d_out;

    char* ws = (char*)d_ws;
    size_t off = 0;
    auto alloc = [&](size_t bytes) -> void* {
        void* p = ws + off;
        off += (bytes + 255) & ~(size_t)255;
        return p;
    };
    // Distinct regions (~93 MB peak):
    __hip_bfloat16* xb     = (__hip_bfloat16*)alloc(4096ULL * 2048 * 2);   // 16 MB
    __hip_bfloat16* wqkv_t = (__hip_bfloat16*)alloc(3072ULL * 2048 * 2);   // 12 MB
    __hip_bfloat16* wo_t   = (__hip_bfloat16*)alloc(2048ULL * 2048 * 2);   // 8 MB
    float*          qkv    = (float*)alloc(4096ULL * 3072 * 4);            // 48 MB
    __hip_bfloat16* Kr     = (__hip_bfloat16*)alloc(2ULL * 4 * 2048 * 128 * 2);  // 4 MB
    __hip_bfloat16* Vt     = (__hip_bfloat16*)alloc(2ULL * 4 * 2048 * 128 * 2);  // 4 MB
    float*          cosT   = (float*)alloc(2048ULL * 64 * 4);
    float*          sinT   = (float*)alloc(2048ULL * 64 * 4);
    // Aliases (regions dead by the time these are written):
    __hip_bfloat16* Qr    = xb;                   // xb dead after QKV GEMM; Qr written after
    __hip_bfloat16* attno = (__hip_bfloat16*)qkv; // qkv dead after rope_scatter; attno written after

    rope_tables<<<dim3(2048), dim3(64), 0, stream>>>(cosT, sinT);
    cast_f32_bf16<<<dim3(8192), dim3(256), 0, stream>>>(x, xb, 2097152);
    transpose_cast<<<dim3(64, 64), dim3(32, 8), 0, stream>>>(Wq, wqkv_t, 2048, 2048);
    transpose_cast<<<dim3(16, 64), dim3(32, 8), 0, stream>>>(Wk, wqkv_t + 2048ULL * 2048, 2048, 512);
    transpose_cast<<<dim3(16, 64), dim3(32, 8), 0, stream>>>(Wv, wqkv_t + 2560ULL * 2048, 2048, 512);
    transpose_cast<<<dim3(64, 64), dim3(32, 8), 0, stream>>>(Wo, wo_t, 2048, 2048);

    gemm_bt_f32<<<dim3(24, 32), dim3(256), 0, stream>>>(xb, wqkv_t, qkv, 4096, 3072, 2048);
    rope_scatter<<<dim3(12, 4096), dim3(256), 0, stream>>>(qkv, cosT, sinT, Qr, Kr, Vt);
    attn_kernel<<<dim3(32, 32), dim3(256), 0, stream>>>(Qr, Kr, Vt, mask, attno);
    gemm_bt_f32<<<dim3(16, 32), dim3(256), 0, stream>>>(attno, wo_t, out, 4096, 2048, 2048);
}

// Round 4
// 489.986 us; speedup vs baseline: 1.0533x; 1.0468x over previous
//
#include <hip/hip_runtime.h>
#include <hip/hip_bf16.h>

typedef __attribute__((ext_vector_type(4))) float f32x4;
typedef __attribute__((ext_vector_type(8))) short s16x8;
typedef __attribute__((ext_vector_type(4))) short s16x4;

// ---------------- RoPE tables (tiny, double precision) ----------------
__global__ void rope_tables(float* __restrict__ cosT, float* __restrict__ sinT) {
    const int s = blockIdx.x, j = threadIdx.x;          // s in [0,2048), j in [0,64)
    const double inv = pow(10000.0, -(double)j / 64.0);
    const double f = (double)s * inv;
    cosT[s * 64 + j] = (float)cos(f);
    sinT[s * 64 + j] = (float)sin(f);
}

// ---------------- cast fp32 -> bf16 (vectorized) ----------------
__global__ __launch_bounds__(256)
void cast_f32_bf16(const float* __restrict__ src, __hip_bfloat16* __restrict__ dst, int n4) {
    const int i = blockIdx.x * 256 + threadIdx.x;
    if (i < n4) {
        f32x4 v = *reinterpret_cast<const f32x4*>(src + (size_t)i * 4);
        union { s16x4 v4; __hip_bfloat16 h[4]; } u;
#pragma unroll
        for (int j = 0; j < 4; ++j) u.h[j] = __float2bfloat16(v[j]);
        *reinterpret_cast<s16x4*>(dst + (size_t)i * 4) = u.v4;
    }
}

// ---------------- tiled transpose + cast: dst[c][r] = (bf16)src[r][c] ----------------
__global__ __launch_bounds__(256)
void transpose_cast(const float* __restrict__ src, __hip_bfloat16* __restrict__ dst,
                    int R, int C) {
    __shared__ __align__(16) float t[32][33];
    const int tx = threadIdx.x, ty = threadIdx.y;       // (32, 8)
    const int r0 = blockIdx.y * 32, c0 = blockIdx.x * 32;
#pragma unroll
    for (int i = 0; i < 32; i += 8)
        t[ty + i][tx] = src[(size_t)(r0 + ty + i) * C + c0 + tx];
    __syncthreads();
#pragma unroll
    for (int i = 0; i < 32; i += 8)
        dst[(size_t)(c0 + ty + i) * R + r0 + tx] = __float2bfloat16(t[tx][ty + i]);
}

// ---------------- m97-style bf16 GEMM: C(f32)[M][N] = A[M][K] * Bt[N][K]^T ----------------
__global__ __launch_bounds__(256)
void gemm_bt_f32(const __hip_bfloat16* __restrict__ A,
                 const __hip_bfloat16* __restrict__ Bt,
                 float* __restrict__ C, int M, int N, int K) {
    __shared__ __align__(16) __hip_bfloat16 As[128 * 32];
    __shared__ __align__(16) __hip_bfloat16 Bs[128 * 32];
    const int tid = threadIdx.x;
    const int l = tid & 63, w = tid >> 6;
    const int row0 = blockIdx.y * 128, col0 = blockIdx.x * 128;
    const int wr = (w >> 1) * 64, wc = (w & 1) * 64;   // wave's 64x64 sub-tile
    f32x4 acc[4][4] = {};
    const int nk = K >> 5;
    for (int ks = 0; ks < nk; ++ks) {
        const int k0 = ks << 5;
#pragma unroll
        for (int i = 0; i < 2; ++i) {
            const int c = i * 256 + tid;               // 16B chunk id, 0..511
            const int r = c >> 2, cc = (c & 3) * 8;    // 4 chunks per 32-col row
            __builtin_amdgcn_global_load_lds(
                (const __attribute__((address_space(1))) void*)(A + (size_t)(row0 + r) * K + k0 + cc),
                (__attribute__((address_space(3))) void*)(As + c * 8), 16, 0, 0);
            __builtin_amdgcn_global_load_lds(
                (const __attribute__((address_space(1))) void*)(Bt + (size_t)(col0 + r) * K + k0 + cc),
                (__attribute__((address_space(3))) void*)(Bs + c * 8), 16, 0, 0);
        }
        __syncthreads();
        s16x8 af[4], bf[4];
#pragma unroll
        for (int mi = 0; mi < 4; ++mi)
            af[mi] = *reinterpret_cast<const s16x8*>(As + (wr + mi * 16 + (l & 15)) * 32 + (l >> 4) * 8);
#pragma unroll
        for (int ni = 0; ni < 4; ++ni)
            bf[ni] = *reinterpret_cast<const s16x8*>(Bs + (wc + ni * 16 + (l & 15)) * 32 + (l >> 4) * 8);
#pragma unroll
        for (int mi = 0; mi < 4; ++mi)
#pragma unroll
            for (int ni = 0; ni < 4; ++ni)
                acc[mi][ni] = __builtin_amdgcn_mfma_f32_16x16x32_bf16(af[mi], bf[ni], acc[mi][ni], 0, 0, 0);
        __syncthreads();
    }
    const int rbase = row0 + wr + ((l >> 4) * 4);
    const int cbase = col0 + wc + (l & 15);
#pragma unroll
    for (int mi = 0; mi < 4; ++mi)
#pragma unroll
        for (int ni = 0; ni < 4; ++ni)
#pragma unroll
            for (int r = 0; r < 4; ++r)
                C[(size_t)(rbase + mi * 16 + r) * N + cbase + ni * 16] = acc[mi][ni][r];
}

// ---------------- RoPE + scatter into attention layouts ----------------
// qkv: f32 [4096][3072] (Q 0..2047 | K 2048..2559 | V 2560..3071)
// Qr: bf16 [2][16][2048][128], Kr: bf16 [2][4][2048][128], Vt: bf16 [2][4][128][2048]
__global__ __launch_bounds__(256)
void rope_scatter(const float* __restrict__ qkv,
                  const float* __restrict__ cosT, const float* __restrict__ sinT,
                  __hip_bfloat16* __restrict__ Qr, __hip_bfloat16* __restrict__ Kr,
                  __hip_bfloat16* __restrict__ Vt) {
    const int m = blockIdx.y;                           // token row, 0..4095
    const int col = blockIdx.x * 256 + threadIdx.x;     // 0..3071
    const int b = m >> 11, s = m & 2047;
    const float v = qkv[(size_t)m * 3072 + col];
    if (col < 2560) {                                   // Q or K: apply RoPE
        const int d = col & 127;                        // head-aligned regions
        const int j = d & 63;
        const float c = cosT[s * 64 + j], sn = sinT[s * 64 + j];
        const float partner = qkv[(size_t)m * 3072 + (col ^ 64)];
        const float rot = (d < 64) ? -partner : partner;
        const float o = v * c + rot * sn;
        if (col < 2048) {
            const int hh = col >> 7;
            Qr[((size_t)(b * 16 + hh) * 2048 + s) * 128 + d] = __float2bfloat16(o);
        } else {
            const int hh = (col - 2048) >> 7;
            Kr[((size_t)(b * 4 + hh) * 2048 + s) * 128 + d] = __float2bfloat16(o);
        }
    } else {                                            // V: transpose-scatter
        const int cc = col - 2560;
        const int hh = cc >> 7, d = cc & 127;
        Vt[((size_t)(b * 4 + hh) * 128 + d) * 2048 + s] = __float2bfloat16(v);
    }
}

// ---------------- flash attention: 64 Q-rows/block, KV tiles of 64 ----------------
// LDS layouts use a chunk-XOR swizzle: 8-bf16 (16B) chunk index c8 of row r is
// stored at physical chunk (c8 ^ (r&7)). Write-side (reg-staged ds_write) and
// read-side use the SAME xor -> bank-conflict-free b128 access, no padding.
__global__ __launch_bounds__(256, 4)
void attn_kernel(const __hip_bfloat16* __restrict__ Qr,
                 const __hip_bfloat16* __restrict__ Kr,
                 const __hip_bfloat16* __restrict__ Vt,
                 const int* __restrict__ mask,
                 __hip_bfloat16* __restrict__ Oo) {
    const int S = 2048;
    const int qt = blockIdx.x;                          // 0..31
    const int bh = blockIdx.y;                          // 0..31
    const int b = bh >> 4, h = bh & 15, kvh = h >> 2;
    const int tid = threadIdx.x;
    const int l = tid & 63, w = tid >> 6;
    const int lo = l & 15, hi = l >> 4;
    __shared__ __align__(16) __hip_bfloat16 Ks[64 * 128];   // [64 kv][128 d], swizzled
    __shared__ __align__(16) __hip_bfloat16 Vs[128 * 64];   // [128 d][64 kv], swizzled
    __shared__ __align__(16) __hip_bfloat16 Ps[4][16 * 64]; // per-wave [16 q][64 kv], swizzled

    const __hip_bfloat16* Qb = Qr + (size_t)(b * 16 + h) * S * 128;
    const __hip_bfloat16* Kb = Kr + (size_t)(b * 4 + kvh) * S * 128;
    const __hip_bfloat16* Vb = Vt + (size_t)(b * 4 + kvh) * 128 * S;

    // Q fragments held in registers: wave owns rows qt*64 + w*16 .. +15
    const int qrow = qt * 64 + w * 16 + lo;
    s16x8 qf[4];
#pragma unroll
    for (int kc = 0; kc < 4; ++kc)
        qf[kc] = *reinterpret_cast<const s16x8*>(Qb + (size_t)qrow * 128 + kc * 32 + hi * 8);

    float m_run[4], l_run[4];
    f32x4 o[8];
#pragma unroll
    for (int r = 0; r < 4; ++r) { m_run[r] = -1e30f; l_run[r] = 0.f; }
#pragma unroll
    for (int n = 0; n < 8; ++n) o[n] = f32x4{0.f, 0.f, 0.f, 0.f};
    const float scale = 0.08838834764831845f;           // 1/sqrt(128)

    // --- staging geometry (constant per thread) ---
    // K tile: 64 rows x 16 chunks; thread's chunk i: row = i*16 + (tid>>4), c8 = tid&15
    // V tile: 128 rows x 8 chunks; thread's chunk i: row = i*32 + (tid>>3), c8 = tid&7
    const int krow = tid >> 4, kc8 = tid & 15;
    const int kdst = krow * 128 + ((kc8 ^ (krow & 7)) * 8);     // + i*16*128
    const int vrow = tid >> 3, vc8 = tid & 7;
    const int vdst = vrow * 64 + ((vc8 ^ (vrow & 7)) * 8);      // + i*32*64

    s16x8 kreg[4], vreg[4];
    auto load_tile = [&](int kv0) {
#pragma unroll
        for (int i = 0; i < 4; ++i)
            kreg[i] = *reinterpret_cast<const s16x8*>(
                Kb + (size_t)(kv0 + i * 16 + krow) * 128 + kc8 * 8);
#pragma unroll
        for (int i = 0; i < 4; ++i)
            vreg[i] = *reinterpret_cast<const s16x8*>(
                Vb + (size_t)(i * 32 + vrow) * S + kv0 + vc8 * 8);
    };

    load_tile(0);
    for (int kt = 0; kt < 32; ++kt) {
        const int kv0 = kt * 64;
        __syncthreads();                                // all waves done reading prev tile
#pragma unroll
        for (int i = 0; i < 4; ++i)
            *reinterpret_cast<s16x8*>(Ks + kdst + i * 2048) = kreg[i];
#pragma unroll
        for (int i = 0; i < 4; ++i)
            *reinterpret_cast<s16x8*>(Vs + vdst + i * 2048) = vreg[i];
        __syncthreads();                                // LDS tile ready
        if (kt < 31) load_tile(kv0 + 64);               // T14: issue early, lands under compute

        // S = Q K^T  (rows q = hi*4+r, col key = ksub*16 + lo)
        f32x4 sc[4] = {};
        __builtin_amdgcn_s_setprio(1);
#pragma unroll
        for (int ksub = 0; ksub < 4; ++ksub) {
            const int kr = ksub * 16 + lo;
            const int ksw = kr & 7;
#pragma unroll
            for (int kc = 0; kc < 4; ++kc) {
                s16x8 kf = *reinterpret_cast<const s16x8*>(
                    Ks + kr * 128 + (((kc * 4 + hi) ^ ksw) * 8));
                sc[ksub] = __builtin_amdgcn_mfma_f32_16x16x32_bf16(qf[kc], kf, sc[ksub], 0, 0, 0);
            }
        }
        __builtin_amdgcn_s_setprio(0);
        // mask + scale
#pragma unroll
        for (int ksub = 0; ksub < 4; ++ksub) {
            const float bias = (mask[b * S + kv0 + ksub * 16 + lo] == 0) ? -1e30f : 0.f;
#pragma unroll
            for (int r = 0; r < 4; ++r) sc[ksub][r] = sc[ksub][r] * scale + bias;
        }
        // online softmax (row reductions across the 16-lane group)
        float alpha[4];
#pragma unroll
        for (int r = 0; r < 4; ++r) {
            float v = fmaxf(fmaxf(sc[0][r], sc[1][r]), fmaxf(sc[2][r], sc[3][r]));
#pragma unroll
            for (int off = 1; off < 16; off <<= 1) v = fmaxf(v, __shfl_xor(v, off));
            const float mnew = fmaxf(m_run[r], v);
            alpha[r] = __expf(m_run[r] - mnew);
            m_run[r] = mnew;
        }
#pragma unroll
        for (int r = 0; r < 4; ++r) {
            float s = 0.f;
#pragma unroll
            for (int ksub = 0; ksub < 4; ++ksub) {
                const float p = __expf(sc[ksub][r] - m_run[r]);
                sc[ksub][r] = p;
                s += p;
            }
#pragma unroll
            for (int off = 1; off < 16; off <<= 1) s += __shfl_xor(s, off);
            l_run[r] = l_run[r] * alpha[r] + s;
        }
#pragma unroll
        for (int n = 0; n < 8; ++n)
#pragma unroll
            for (int r = 0; r < 4; ++r) o[n][r] *= alpha[r];
        // P -> LDS (bf16), swizzled, wave-private (no barrier needed)
        __hip_bfloat16* pb = &Ps[w][0];
#pragma unroll
        for (int ksub = 0; ksub < 4; ++ksub) {
            const int pchunk = ksub * 2 + (lo >> 3);
#pragma unroll
            for (int r = 0; r < 4; ++r) {
                const int prow = hi * 4 + r;
                pb[prow * 64 + ((pchunk ^ (prow & 7)) * 8) + (lo & 7)] =
                    __float2bfloat16(sc[ksub][r]);
            }
        }
        // O += P V
        __builtin_amdgcn_s_setprio(1);
#pragma unroll
        for (int kg = 0; kg < 2; ++kg) {
            s16x8 pa = *reinterpret_cast<const s16x8*>(
                pb + lo * 64 + (((kg * 4 + hi) ^ (lo & 7)) * 8));
#pragma unroll
            for (int n = 0; n < 8; ++n) {
                const int vr = n * 16 + lo;
                s16x8 vb = *reinterpret_cast<const s16x8*>(
                    Vs + vr * 64 + (((kg * 4 + hi) ^ (vr & 7)) * 8));
                o[n] = __builtin_amdgcn_mfma_f32_16x16x32_bf16(pa, vb, o[n], 0, 0, 0);
            }
        }
        __builtin_amdgcn_s_setprio(0);
    }
    // epilogue: attn_out[b*S+s][h*128+d] = o / l
    const int orow = b * S + qt * 64 + w * 16 + (hi * 4);
    const int ocol = h * 128 + lo;
#pragma unroll
    for (int n = 0; n < 8; ++n)
#pragma unroll
        for (int r = 0; r < 4; ++r)
            Oo[(size_t)(orow + r) * 2048 + ocol + n * 16] = __float2bfloat16(o[n][r] / l_run[r]);
}

// ---------------- host launch ----------------
extern "C" void kernel_launch(void* const* d_in, const int* in_sizes, int n_in,
                              void* d_out, int out_size, void* d_ws, size_t ws_size,
                              hipStream_t stream) {
    const float* x  = (const float*)d_in[0];
    const int* mask = (const int*)d_in[1];
    const float* Wq = (const float*)d_in[2];
    const float* Wk = (const float*)d_in[3];
    const float* Wv = (const float*)d_in[4];
    const float* Wo = (const float*)d_in[5];
    float* out = (float*)d_out;

    char* ws = (char*)d_ws;
    size_t off = 0;
    auto alloc = [&](size_t bytes) -> void* {
        void* p = ws + off;
        off += (bytes + 255) & ~(size_t)255;
        return p;
    };
    // Distinct regions (~93 MB peak):
    __hip_bfloat16* xb     = (__hip_bfloat16*)alloc(4096ULL * 2048 * 2);   // 16 MB
    __hip_bfloat16* wqkv_t = (__hip_bfloat16*)alloc(3072ULL * 2048 * 2);   // 12 MB
    __hip_bfloat16* wo_t   = (__hip_bfloat16*)alloc(2048ULL * 2048 * 2);   // 8 MB
    float*          qkv    = (float*)alloc(4096ULL * 3072 * 4);            // 48 MB
    __hip_bfloat16* Kr     = (__hip_bfloat16*)alloc(2ULL * 4 * 2048 * 128 * 2);  // 4 MB
    __hip_bfloat16* Vt     = (__hip_bfloat16*)alloc(2ULL * 4 * 2048 * 128 * 2);  // 4 MB
    float*          cosT   = (float*)alloc(2048ULL * 64 * 4);
    float*          sinT   = (float*)alloc(2048ULL * 64 * 4);
    // Aliases (regions dead by the time these are written):
    __hip_bfloat16* Qr    = xb;                   // xb dead after QKV GEMM; Qr written after
    __hip_bfloat16* attno = (__hip_bfloat16*)qkv; // qkv dead after rope_scatter; attno written after

    rope_tables<<<dim3(2048), dim3(64), 0, stream>>>(cosT, sinT);
    cast_f32_bf16<<<dim3(8192), dim3(256), 0, stream>>>(x, xb, 2097152);
    transpose_cast<<<dim3(64, 64), dim3(32, 8), 0, stream>>>(Wq, wqkv_t, 2048, 2048);
    transpose_cast<<<dim3(16, 64), dim3(32, 8), 0, stream>>>(Wk, wqkv_t + 2048ULL * 2048, 2048, 512);
    transpose_cast<<<dim3(16, 64), dim3(32, 8), 0, stream>>>(Wv, wqkv_t + 2560ULL * 2048, 2048, 512);
    transpose_cast<<<dim3(64, 64), dim3(32, 8), 0, stream>>>(Wo, wo_t, 2048, 2048);

    gemm_bt_f32<<<dim3(24, 32), dim3(256), 0, stream>>>(xb, wqkv_t, qkv, 4096, 3072, 2048);
    rope_scatter<<<dim3(12, 4096), dim3(256), 0, stream>>>(qkv, cosT, sinT, Qr, Kr, Vt);
    attn_kernel<<<dim3(32, 32), dim3(256), 0, stream>>>(Qr, Kr, Vt, mask, attno);
    gemm_bt_f32<<<dim3(16, 32), dim3(256), 0, stream>>>(attno, wo_t, out, 4096, 2048, 2048);
}

// Round 5
// 351.974 us; speedup vs baseline: 1.4663x; 1.3921x over previous
//
#include <hip/hip_runtime.h>
#include <hip/hip_bf16.h>

typedef __attribute__((ext_vector_type(4))) float f32x4;
typedef __attribute__((ext_vector_type(8))) short s16x8;
typedef __attribute__((ext_vector_type(4))) short s16x4;

// ---------------- RoPE tables (tiny, double precision) ----------------
__global__ void rope_tables(float* __restrict__ cosT, float* __restrict__ sinT) {
    const int s = blockIdx.x, j = threadIdx.x;          // s in [0,2048), j in [0,64)
    const double inv = pow(10000.0, -(double)j / 64.0);
    const double f = (double)s * inv;
    cosT[s * 64 + j] = (float)cos(f);
    sinT[s * 64 + j] = (float)sin(f);
}

// ---------------- cast fp32 -> bf16 (vectorized) ----------------
__global__ __launch_bounds__(256)
void cast_f32_bf16(const float* __restrict__ src, __hip_bfloat16* __restrict__ dst, int n4) {
    const int i = blockIdx.x * 256 + threadIdx.x;
    if (i < n4) {
        f32x4 v = *reinterpret_cast<const f32x4*>(src + (size_t)i * 4);
        union { s16x4 v4; __hip_bfloat16 h[4]; } u;
#pragma unroll
        for (int j = 0; j < 4; ++j) u.h[j] = __float2bfloat16(v[j]);
        *reinterpret_cast<s16x4*>(dst + (size_t)i * 4) = u.v4;
    }
}

// ---------------- tiled transpose + cast: dst[c][r] = (bf16)src[r][c] ----------------
__global__ __launch_bounds__(256)
void transpose_cast(const float* __restrict__ src, __hip_bfloat16* __restrict__ dst,
                    int R, int C) {
    __shared__ __align__(16) float t[32][33];
    const int tx = threadIdx.x, ty = threadIdx.y;       // (32, 8)
    const int r0 = blockIdx.y * 32, c0 = blockIdx.x * 32;
#pragma unroll
    for (int i = 0; i < 32; i += 8)
        t[ty + i][tx] = src[(size_t)(r0 + ty + i) * C + c0 + tx];
    __syncthreads();
#pragma unroll
    for (int i = 0; i < 32; i += 8)
        dst[(size_t)(c0 + ty + i) * R + r0 + tx] = __float2bfloat16(t[tx][ty + i]);
}

// ---------------- m97-style bf16 GEMM: C(f32)[M][N] = A[M][K] * Bt[N][K]^T ----------------
__global__ __launch_bounds__(256)
void gemm_bt_f32(const __hip_bfloat16* __restrict__ A,
                 const __hip_bfloat16* __restrict__ Bt,
                 float* __restrict__ C, int M, int N, int K) {
    __shared__ __align__(16) __hip_bfloat16 As[128 * 32];
    __shared__ __align__(16) __hip_bfloat16 Bs[128 * 32];
    const int tid = threadIdx.x;
    const int l = tid & 63, w = tid >> 6;
    const int row0 = blockIdx.y * 128, col0 = blockIdx.x * 128;
    const int wr = (w >> 1) * 64, wc = (w & 1) * 64;   // wave's 64x64 sub-tile
    f32x4 acc[4][4] = {};
    const int nk = K >> 5;
    for (int ks = 0; ks < nk; ++ks) {
        const int k0 = ks << 5;
#pragma unroll
        for (int i = 0; i < 2; ++i) {
            const int c = i * 256 + tid;               // 16B chunk id, 0..511
            const int r = c >> 2, cc = (c & 3) * 8;    // 4 chunks per 32-col row
            __builtin_amdgcn_global_load_lds(
                (const __attribute__((address_space(1))) void*)(A + (size_t)(row0 + r) * K + k0 + cc),
                (__attribute__((address_space(3))) void*)(As + c * 8), 16, 0, 0);
            __builtin_amdgcn_global_load_lds(
                (const __attribute__((address_space(1))) void*)(Bt + (size_t)(col0 + r) * K + k0 + cc),
                (__attribute__((address_space(3))) void*)(Bs + c * 8), 16, 0, 0);
        }
        __syncthreads();
        s16x8 af[4], bf[4];
#pragma unroll
        for (int mi = 0; mi < 4; ++mi)
            af[mi] = *reinterpret_cast<const s16x8*>(As + (wr + mi * 16 + (l & 15)) * 32 + (l >> 4) * 8);
#pragma unroll
        for (int ni = 0; ni < 4; ++ni)
            bf[ni] = *reinterpret_cast<const s16x8*>(Bs + (wc + ni * 16 + (l & 15)) * 32 + (l >> 4) * 8);
#pragma unroll
        for (int mi = 0; mi < 4; ++mi)
#pragma unroll
            for (int ni = 0; ni < 4; ++ni)
                acc[mi][ni] = __builtin_amdgcn_mfma_f32_16x16x32_bf16(af[mi], bf[ni], acc[mi][ni], 0, 0, 0);
        __syncthreads();
    }
    const int rbase = row0 + wr + ((l >> 4) * 4);
    const int cbase = col0 + wc + (l & 15);
#pragma unroll
    for (int mi = 0; mi < 4; ++mi)
#pragma unroll
        for (int ni = 0; ni < 4; ++ni)
#pragma unroll
            for (int r = 0; r < 4; ++r)
                C[(size_t)(rbase + mi * 16 + r) * N + cbase + ni * 16] = acc[mi][ni][r];
}

// ---------------- RoPE + scatter into attention layouts ----------------
// qkv: f32 [4096][3072] (Q 0..2047 | K 2048..2559 | V 2560..3071)
// Qr: bf16 [2][16][2048][128], Kr: bf16 [2][4][2048][128], Vt: bf16 [2][4][128][2048]
__global__ __launch_bounds__(256)
void rope_scatter(const float* __restrict__ qkv,
                  const float* __restrict__ cosT, const float* __restrict__ sinT,
                  __hip_bfloat16* __restrict__ Qr, __hip_bfloat16* __restrict__ Kr,
                  __hip_bfloat16* __restrict__ Vt) {
    const int m = blockIdx.y;                           // token row, 0..4095
    const int col = blockIdx.x * 256 + threadIdx.x;     // 0..3071
    const int b = m >> 11, s = m & 2047;
    const float v = qkv[(size_t)m * 3072 + col];
    if (col < 2560) {                                   // Q or K: apply RoPE
        const int d = col & 127;                        // head-aligned regions
        const int j = d & 63;
        const float c = cosT[s * 64 + j], sn = sinT[s * 64 + j];
        const float partner = qkv[(size_t)m * 3072 + (col ^ 64)];
        const float rot = (d < 64) ? -partner : partner;
        const float o = v * c + rot * sn;
        if (col < 2048) {
            const int hh = col >> 7;
            Qr[((size_t)(b * 16 + hh) * 2048 + s) * 128 + d] = __float2bfloat16(o);
        } else {
            const int hh = (col - 2048) >> 7;
            Kr[((size_t)(b * 4 + hh) * 2048 + s) * 128 + d] = __float2bfloat16(o);
        }
    } else {                                            // V: transpose-scatter
        const int cc = col - 2560;
        const int hh = cc >> 7, d = cc & 127;
        Vt[((size_t)(b * 4 + hh) * 128 + d) * 2048 + s] = __float2bfloat16(v);
    }
}

// ---------------- flash attention: 64 Q-rows/block, KV tiles of 64 ----------------
// Swapped QK^T (T12): mfma(kf, qf) puts P^T in regs -> lane holds 16 kv-values of
// ONE q-row (q = l&15). Softmax is in-lane tree + 2 shfl_xor. P -> LDS via
// cvt_pk (4x ds_write_b64). LDS chunk-XOR swizzle: 16B chunk c8 of row r at
// physical chunk (c8 ^ (r&7)) on both write and read sides.
__global__ __launch_bounds__(256, 4)
void attn_kernel(const __hip_bfloat16* __restrict__ Qr,
                 const __hip_bfloat16* __restrict__ Kr,
                 const __hip_bfloat16* __restrict__ Vt,
                 const int* __restrict__ mask,
                 __hip_bfloat16* __restrict__ Oo) {
    const int S = 2048;
    const int qt = blockIdx.x;                          // 0..31
    const int bh = blockIdx.y;                          // 0..31
    const int b = bh >> 4, h = bh & 15, kvh = h >> 2;
    const int tid = threadIdx.x;
    const int l = tid & 63, w = tid >> 6;
    const int lo = l & 15, hi = l >> 4;
    __shared__ __align__(16) __hip_bfloat16 Ks[64 * 128];   // [64 kv][128 d], swizzled
    __shared__ __align__(16) __hip_bfloat16 Vs[128 * 64];   // [128 d][64 kv], swizzled
    __shared__ __align__(16) __hip_bfloat16 Ps[4][16 * 64]; // per-wave [16 q][64 kv], swizzled

    const __hip_bfloat16* Qb = Qr + (size_t)(b * 16 + h) * S * 128;
    const __hip_bfloat16* Kb = Kr + (size_t)(b * 4 + kvh) * S * 128;
    const __hip_bfloat16* Vb = Vt + (size_t)(b * 4 + kvh) * 128 * S;

    // Q fragments held in registers: wave owns rows qt*64 + w*16 .. +15
    const int qrow = qt * 64 + w * 16 + lo;
    s16x8 qf[4];
#pragma unroll
    for (int kc = 0; kc < 4; ++kc)
        qf[kc] = *reinterpret_cast<const s16x8*>(Qb + (size_t)qrow * 128 + kc * 32 + hi * 8);

    float m_run = -1e30f, l_run = 0.f;                  // scalar: this lane's q-row is lo
    f32x4 o[8];
#pragma unroll
    for (int n = 0; n < 8; ++n) o[n] = f32x4{0.f, 0.f, 0.f, 0.f};
    const float scale = 0.08838834764831845f;           // 1/sqrt(128)

    // --- staging geometry (constant per thread) ---
    const int krow = tid >> 4, kc8 = tid & 15;
    const int kdst = krow * 128 + ((kc8 ^ (krow & 7)) * 8);     // + i*16*128
    const int vrow = tid >> 3, vc8 = tid & 7;
    const int vdst = vrow * 64 + ((vc8 ^ (vrow & 7)) * 8);      // + i*32*64

    s16x8 kreg[4], vreg[4];
    auto load_tile = [&](int kv0) {
#pragma unroll
        for (int i = 0; i < 4; ++i)
            kreg[i] = *reinterpret_cast<const s16x8*>(
                Kb + (size_t)(kv0 + i * 16 + krow) * 128 + kc8 * 8);
#pragma unroll
        for (int i = 0; i < 4; ++i)
            vreg[i] = *reinterpret_cast<const s16x8*>(
                Vb + (size_t)(i * 32 + vrow) * S + kv0 + vc8 * 8);
    };

    load_tile(0);
    for (int kt = 0; kt < 32; ++kt) {
        const int kv0 = kt * 64;
        // mask words for this tile (issued before prefetch -> no vmcnt drain)
        int4 mi[4];
#pragma unroll
        for (int ksub = 0; ksub < 4; ++ksub)
            mi[ksub] = *reinterpret_cast<const int4*>(mask + b * S + kv0 + ksub * 16 + hi * 4);

        __syncthreads();                                // all waves done reading prev tile
#pragma unroll
        for (int i = 0; i < 4; ++i)
            *reinterpret_cast<s16x8*>(Ks + kdst + i * 2048) = kreg[i];
#pragma unroll
        for (int i = 0; i < 4; ++i)
            *reinterpret_cast<s16x8*>(Vs + vdst + i * 2048) = vreg[i];
        __syncthreads();                                // LDS tile ready
        if (kt < 31) load_tile(kv0 + 64);               // T14: lands under compute

        // P^T = (K Q^T): lane holds P[kv=ksub*16+hi*4+r][q=lo]
        f32x4 sc[4] = {};
        __builtin_amdgcn_s_setprio(1);
#pragma unroll
        for (int ksub = 0; ksub < 4; ++ksub) {
            const int kr = ksub * 16 + lo;
            const int ksw = kr & 7;
#pragma unroll
            for (int kc = 0; kc < 4; ++kc) {
                s16x8 kf = *reinterpret_cast<const s16x8*>(
                    Ks + kr * 128 + (((kc * 4 + hi) ^ ksw) * 8));
                sc[ksub] = __builtin_amdgcn_mfma_f32_16x16x32_bf16(kf, qf[kc], sc[ksub], 0, 0, 0);
            }
        }
        __builtin_amdgcn_s_setprio(0);
        // scale + additive mask bias (per-reg kv index)
#pragma unroll
        for (int ksub = 0; ksub < 4; ++ksub) {
            const int* mw = (const int*)&mi[ksub];
#pragma unroll
            for (int r = 0; r < 4; ++r)
                sc[ksub][r] = sc[ksub][r] * scale + (mw[r] == 0 ? -1e30f : 0.f);
        }
        // in-register online softmax for q-row lo
        float a0 = fmaxf(fmaxf(sc[0][0], sc[0][1]), fmaxf(sc[0][2], sc[0][3]));
        float a1 = fmaxf(fmaxf(sc[1][0], sc[1][1]), fmaxf(sc[1][2], sc[1][3]));
        float a2 = fmaxf(fmaxf(sc[2][0], sc[2][1]), fmaxf(sc[2][2], sc[2][3]));
        float a3 = fmaxf(fmaxf(sc[3][0], sc[3][1]), fmaxf(sc[3][2], sc[3][3]));
        float mx = fmaxf(fmaxf(a0, a1), fmaxf(a2, a3));
        mx = fmaxf(mx, __shfl_xor(mx, 16));
        mx = fmaxf(mx, __shfl_xor(mx, 32));
        const float mnew = fmaxf(m_run, mx);
        const float alpha = __expf(m_run - mnew);
        m_run = mnew;
        float s0 = 0.f, s1 = 0.f, s2 = 0.f, s3 = 0.f;
#pragma unroll
        for (int r = 0; r < 4; ++r) {
            sc[0][r] = __expf(sc[0][r] - mnew); s0 += sc[0][r];
            sc[1][r] = __expf(sc[1][r] - mnew); s1 += sc[1][r];
            sc[2][r] = __expf(sc[2][r] - mnew); s2 += sc[2][r];
            sc[3][r] = __expf(sc[3][r] - mnew); s3 += sc[3][r];
        }
        float ssum = (s0 + s1) + (s2 + s3);
        ssum += __shfl_xor(ssum, 16);
        ssum += __shfl_xor(ssum, 32);
        l_run = l_run * alpha + ssum;
        // rescale O (alpha lives at lane q; o rows are hi*4+r)
        float ar[4];
#pragma unroll
        for (int r = 0; r < 4; ++r) ar[r] = __shfl(alpha, hi * 4 + r);
#pragma unroll
        for (int n = 0; n < 8; ++n)
#pragma unroll
            for (int r = 0; r < 4; ++r) o[n][r] *= ar[r];
        // P -> LDS: cvt_pk pairs, one b64 per ksub (row q=lo, cols ksub*16+hi*4..+3)
        __hip_bfloat16* pb = &Ps[w][0];
#pragma unroll
        for (int ksub = 0; ksub < 4; ++ksub) {
            unsigned int d0, d1;
            asm("v_cvt_pk_bf16_f32 %0, %1, %2" : "=v"(d0) : "v"(sc[ksub][0]), "v"(sc[ksub][1]));
            asm("v_cvt_pk_bf16_f32 %0, %1, %2" : "=v"(d1) : "v"(sc[ksub][2]), "v"(sc[ksub][3]));
            const int byteoff = lo * 128 + (((ksub * 2 + (hi >> 1)) ^ (lo & 7)) * 16) + (hi & 1) * 8;
            uint2 dd; dd.x = d0; dd.y = d1;
            *reinterpret_cast<uint2*>(reinterpret_cast<char*>(pb) + byteoff) = dd;
        }
        // O += P V
        __builtin_amdgcn_s_setprio(1);
#pragma unroll
        for (int kg = 0; kg < 2; ++kg) {
            s16x8 pa = *reinterpret_cast<const s16x8*>(
                pb + lo * 64 + (((kg * 4 + hi) ^ (lo & 7)) * 8));
#pragma unroll
            for (int n = 0; n < 8; ++n) {
                const int vr = n * 16 + lo;
                s16x8 vb = *reinterpret_cast<const s16x8*>(
                    Vs + vr * 64 + (((kg * 4 + hi) ^ (vr & 7)) * 8));
                o[n] = __builtin_amdgcn_mfma_f32_16x16x32_bf16(pa, vb, o[n], 0, 0, 0);
            }
        }
        __builtin_amdgcn_s_setprio(0);
    }
    // epilogue: attn_out[b*S+s][h*128+d] = o / l   (l lives at lane q)
    float lr[4];
#pragma unroll
    for (int r = 0; r < 4; ++r) lr[r] = __shfl(l_run, hi * 4 + r);
    const int orow = b * S + qt * 64 + w * 16 + (hi * 4);
    const int ocol = h * 128 + lo;
#pragma unroll
    for (int n = 0; n < 8; ++n)
#pragma unroll
        for (int r = 0; r < 4; ++r)
            Oo[(size_t)(orow + r) * 2048 + ocol + n * 16] = __float2bfloat16(o[n][r] / lr[r]);
}

// ---------------- host launch ----------------
extern "C" void kernel_launch(void* const* d_in, const int* in_sizes, int n_in,
                              void* d_out, int out_size, void* d_ws, size_t ws_size,
                              hipStream_t stream) {
    const float* x  = (const float*)d_in[0];
    const int* mask = (const int*)d_in[1];
    const float* Wq = (const float*)d_in[2];
    const float* Wk = (const float*)d_in[3];
    const float* Wv = (const float*)d_in[4];
    const float* Wo = (const float*)d_in[5];
    float* out = (float*)d_out;

    char* ws = (char*)d_ws;
    size_t off = 0;
    auto alloc = [&](size_t bytes) -> void* {
        void* p = ws + off;
        off += (bytes + 255) & ~(size_t)255;
        return p;
    };
    // Distinct regions (~93 MB peak):
    __hip_bfloat16* xb     = (__hip_bfloat16*)alloc(4096ULL * 2048 * 2);   // 16 MB
    __hip_bfloat16* wqkv_t = (__hip_bfloat16*)alloc(3072ULL * 2048 * 2);   // 12 MB
    __hip_bfloat16* wo_t   = (__hip_bfloat16*)alloc(2048ULL * 2048 * 2);   // 8 MB
    float*          qkv    = (float*)alloc(4096ULL * 3072 * 4);            // 48 MB
    __hip_bfloat16* Kr     = (__hip_bfloat16*)alloc(2ULL * 4 * 2048 * 128 * 2);  // 4 MB
    __hip_bfloat16* Vt     = (__hip_bfloat16*)alloc(2ULL * 4 * 2048 * 128 * 2);  // 4 MB
    float*          cosT   = (float*)alloc(2048ULL * 64 * 4);
    float*          sinT   = (float*)alloc(2048ULL * 64 * 4);
    // Aliases (regions dead by the time these are written):
    __hip_bfloat16* Qr    = xb;                   // xb dead after QKV GEMM; Qr written after
    __hip_bfloat16* attno = (__hip_bfloat16*)qkv; // qkv dead after rope_scatter; attno written after

    rope_tables<<<dim3(2048), dim3(64), 0, stream>>>(cosT, sinT);
    cast_f32_bf16<<<dim3(8192), dim3(256), 0, stream>>>(x, xb, 2097152);
    transpose_cast<<<dim3(64, 64), dim3(32, 8), 0, stream>>>(Wq, wqkv_t, 2048, 2048);
    transpose_cast<<<dim3(16, 64), dim3(32, 8), 0, stream>>>(Wk, wqkv_t + 2048ULL * 2048, 2048, 512);
    transpose_cast<<<dim3(16, 64), dim3(32, 8), 0, stream>>>(Wv, wqkv_t + 2560ULL * 2048, 2048, 512);
    transpose_cast<<<dim3(64, 64), dim3(32, 8), 0, stream>>>(Wo, wo_t, 2048, 2048);

    gemm_bt_f32<<<dim3(24, 32), dim3(256), 0, stream>>>(xb, wqkv_t, qkv, 4096, 3072, 2048);
    rope_scatter<<<dim3(12, 4096), dim3(256), 0, stream>>>(qkv, cosT, sinT, Qr, Kr, Vt);
    attn_kernel<<<dim3(32, 32), dim3(256), 0, stream>>>(Qr, Kr, Vt, mask, attno);
    gemm_bt_f32<<<dim3(16, 32), dim3(256), 0, stream>>>(attno, wo_t, out, 4096, 2048, 2048);
}

// Round 6
// 286.746 us; speedup vs baseline: 1.7999x; 1.2275x over previous
//
#include <hip/hip_runtime.h>
#include <hip/hip_bf16.h>

typedef __attribute__((ext_vector_type(4))) float f32x4;
typedef __attribute__((ext_vector_type(8))) short s16x8;
typedef __attribute__((ext_vector_type(4))) short s16x4;

// ---------------- RoPE tables (tiny, double precision) ----------------
__global__ void rope_tables(float* __restrict__ cosT, float* __restrict__ sinT) {
    const int s = blockIdx.x, j = threadIdx.x;          // s in [0,2048), j in [0,64)
    const double inv = pow(10000.0, -(double)j / 64.0);
    const double f = (double)s * inv;
    cosT[s * 64 + j] = (float)cos(f);
    sinT[s * 64 + j] = (float)sin(f);
}

// ---------------- cast fp32 -> bf16 (vectorized) ----------------
__global__ __launch_bounds__(256)
void cast_f32_bf16(const float* __restrict__ src, __hip_bfloat16* __restrict__ dst, int n4) {
    const int i = blockIdx.x * 256 + threadIdx.x;
    if (i < n4) {
        f32x4 v = *reinterpret_cast<const f32x4*>(src + (size_t)i * 4);
        union { s16x4 v4; __hip_bfloat16 h[4]; } u;
#pragma unroll
        for (int j = 0; j < 4; ++j) u.h[j] = __float2bfloat16(v[j]);
        *reinterpret_cast<s16x4*>(dst + (size_t)i * 4) = u.v4;
    }
}

// ---------------- tiled transpose + cast: dst[c][r] = (bf16)src[r][c] ----------------
__global__ __launch_bounds__(256)
void transpose_cast(const float* __restrict__ src, __hip_bfloat16* __restrict__ dst,
                    int R, int C) {
    __shared__ __align__(16) float t[32][33];
    const int tx = threadIdx.x, ty = threadIdx.y;       // (32, 8)
    const int r0 = blockIdx.y * 32, c0 = blockIdx.x * 32;
#pragma unroll
    for (int i = 0; i < 32; i += 8)
        t[ty + i][tx] = src[(size_t)(r0 + ty + i) * C + c0 + tx];
    __syncthreads();
#pragma unroll
    for (int i = 0; i < 32; i += 8)
        dst[(size_t)(c0 + ty + i) * R + r0 + tx] = __float2bfloat16(t[tx][ty + i]);
}

// ---------------- m97-style bf16 GEMM: C(f32)[M][N] = A[M][K] * Bt[N][K]^T ----------------
__global__ __launch_bounds__(256)
void gemm_bt_f32(const __hip_bfloat16* __restrict__ A,
                 const __hip_bfloat16* __restrict__ Bt,
                 float* __restrict__ C, int M, int N, int K) {
    __shared__ __align__(16) __hip_bfloat16 As[128 * 32];
    __shared__ __align__(16) __hip_bfloat16 Bs[128 * 32];
    const int tid = threadIdx.x;
    const int l = tid & 63, w = tid >> 6;
    const int row0 = blockIdx.y * 128, col0 = blockIdx.x * 128;
    const int wr = (w >> 1) * 64, wc = (w & 1) * 64;   // wave's 64x64 sub-tile
    f32x4 acc[4][4] = {};
    const int nk = K >> 5;
    for (int ks = 0; ks < nk; ++ks) {
        const int k0 = ks << 5;
#pragma unroll
        for (int i = 0; i < 2; ++i) {
            const int c = i * 256 + tid;               // 16B chunk id, 0..511
            const int r = c >> 2, cc = (c & 3) * 8;    // 4 chunks per 32-col row
            __builtin_amdgcn_global_load_lds(
                (const __attribute__((address_space(1))) void*)(A + (size_t)(row0 + r) * K + k0 + cc),
                (__attribute__((address_space(3))) void*)(As + c * 8), 16, 0, 0);
            __builtin_amdgcn_global_load_lds(
                (const __attribute__((address_space(1))) void*)(Bt + (size_t)(col0 + r) * K + k0 + cc),
                (__attribute__((address_space(3))) void*)(Bs + c * 8), 16, 0, 0);
        }
        __syncthreads();
        s16x8 af[4], bf[4];
#pragma unroll
        for (int mi = 0; mi < 4; ++mi)
            af[mi] = *reinterpret_cast<const s16x8*>(As + (wr + mi * 16 + (l & 15)) * 32 + (l >> 4) * 8);
#pragma unroll
        for (int ni = 0; ni < 4; ++ni)
            bf[ni] = *reinterpret_cast<const s16x8*>(Bs + (wc + ni * 16 + (l & 15)) * 32 + (l >> 4) * 8);
#pragma unroll
        for (int mi = 0; mi < 4; ++mi)
#pragma unroll
            for (int ni = 0; ni < 4; ++ni)
                acc[mi][ni] = __builtin_amdgcn_mfma_f32_16x16x32_bf16(af[mi], bf[ni], acc[mi][ni], 0, 0, 0);
        __syncthreads();
    }
    const int rbase = row0 + wr + ((l >> 4) * 4);
    const int cbase = col0 + wc + (l & 15);
#pragma unroll
    for (int mi = 0; mi < 4; ++mi)
#pragma unroll
        for (int ni = 0; ni < 4; ++ni)
#pragma unroll
            for (int r = 0; r < 4; ++r)
                C[(size_t)(rbase + mi * 16 + r) * N + cbase + ni * 16] = acc[mi][ni][r];
}

// ---------------- RoPE + scatter into attention layouts ----------------
// qkv: f32 [4096][3072] (Q 0..2047 | K 2048..2559 | V 2560..3071)
// Qr: bf16 [2][16][2048][128], Kr: bf16 [2][4][2048][128], Vt: bf16 [2][4][128][2048]
__global__ __launch_bounds__(256)
void rope_scatter(const float* __restrict__ qkv,
                  const float* __restrict__ cosT, const float* __restrict__ sinT,
                  __hip_bfloat16* __restrict__ Qr, __hip_bfloat16* __restrict__ Kr,
                  __hip_bfloat16* __restrict__ Vt) {
    const int m = blockIdx.y;                           // token row, 0..4095
    const int col = blockIdx.x * 256 + threadIdx.x;     // 0..3071
    const int b = m >> 11, s = m & 2047;
    const float v = qkv[(size_t)m * 3072 + col];
    if (col < 2560) {                                   // Q or K: apply RoPE
        const int d = col & 127;                        // head-aligned regions
        const int j = d & 63;
        const float c = cosT[s * 64 + j], sn = sinT[s * 64 + j];
        const float partner = qkv[(size_t)m * 3072 + (col ^ 64)];
        const float rot = (d < 64) ? -partner : partner;
        const float o = v * c + rot * sn;
        if (col < 2048) {
            const int hh = col >> 7;
            Qr[((size_t)(b * 16 + hh) * 2048 + s) * 128 + d] = __float2bfloat16(o);
        } else {
            const int hh = (col - 2048) >> 7;
            Kr[((size_t)(b * 4 + hh) * 2048 + s) * 128 + d] = __float2bfloat16(o);
        }
    } else {                                            // V: transpose-scatter
        const int cc = col - 2560;
        const int hh = cc >> 7, d = cc & 127;
        Vt[((size_t)(b * 4 + hh) * 128 + d) * 2048 + s] = __float2bfloat16(v);
    }
}

// ---------------- flash attention: 128 Q-rows/block (8 waves), KV tiles of 64 ----------------
// Swapped QK^T (T12): mfma(kf, qf) puts P^T in regs -> lane holds 16 kv-values of
// ONE q-row (q = l&15); softmax in-lane + 2 shfl_xor. Double-buffered K/V LDS,
// ONE barrier per tile (write buf[t&1] is disjoint from all in-flight reads of
// buf[(t-1)&1]). Defer-max (T13, THR=8) skips the O-rescale on stable-max tiles.
// Chunk-XOR swizzle on all LDS tiles (same xor on write and read sides).
__global__ __launch_bounds__(512, 4)
void attn_kernel(const __hip_bfloat16* __restrict__ Qr,
                 const __hip_bfloat16* __restrict__ Kr,
                 const __hip_bfloat16* __restrict__ Vt,
                 const int* __restrict__ mask,
                 __hip_bfloat16* __restrict__ Oo) {
    const int S = 2048;
    const int qt = blockIdx.x;                          // 0..15 (128 q-rows per block)
    const int bh = blockIdx.y;                          // 0..31
    const int b = bh >> 4, h = bh & 15, kvh = h >> 2;
    const int tid = threadIdx.x;
    const int l = tid & 63, w = tid >> 6;               // 8 waves
    const int lo = l & 15, hi = l >> 4;
    __shared__ __align__(16) __hip_bfloat16 Ks[2][64 * 128];   // [kv][d], swizzled
    __shared__ __align__(16) __hip_bfloat16 Vs[2][128 * 64];   // [d][kv], swizzled
    __shared__ __align__(16) __hip_bfloat16 Ps[8][16 * 64];    // per-wave [q][kv], swizzled

    const __hip_bfloat16* Qb = Qr + (size_t)(b * 16 + h) * S * 128;
    const __hip_bfloat16* Kb = Kr + (size_t)(b * 4 + kvh) * S * 128;
    const __hip_bfloat16* Vb = Vt + (size_t)(b * 4 + kvh) * 128 * S;

    // Q fragments in registers: wave owns rows qt*128 + w*16 .. +15
    const int qrow = qt * 128 + w * 16 + lo;
    s16x8 qf[4];
#pragma unroll
    for (int kc = 0; kc < 4; ++kc)
        qf[kc] = *reinterpret_cast<const s16x8*>(Qb + (size_t)qrow * 128 + kc * 32 + hi * 8);

    float m_run = -1e30f, l_run = 0.f;                  // this lane's q-row is lo
    f32x4 o[8];
#pragma unroll
    for (int n = 0; n < 8; ++n) o[n] = f32x4{0.f, 0.f, 0.f, 0.f};
    const float scale = 0.08838834764831845f;           // 1/sqrt(128)

    // --- staging geometry: 512 threads stage K (64x16 chunks) and V (128x8 chunks), 2 each ---
    const int krow = tid >> 4, kc8 = tid & 15;          // krow 0..31 (+i*32)
    const int koff = (kc8 ^ (krow & 7)) * 8;            // 32 % 8 == 0 -> same swz both i
    const int vrow = tid >> 3, vc8 = tid & 7;           // vrow 0..63 (+i*64)
    const int voff = (vc8 ^ (vrow & 7)) * 8;

    s16x8 kreg[2], vreg[2];
    auto load_tile = [&](int kv0) {
#pragma unroll
        for (int i = 0; i < 2; ++i)
            kreg[i] = *reinterpret_cast<const s16x8*>(
                Kb + (size_t)(kv0 + i * 32 + krow) * 128 + kc8 * 8);
#pragma unroll
        for (int i = 0; i < 2; ++i)
            vreg[i] = *reinterpret_cast<const s16x8*>(
                Vb + (size_t)(i * 64 + vrow) * S + kv0 + vc8 * 8);
    };

    load_tile(0);
    for (int kt = 0; kt < 32; ++kt) {
        const int kv0 = kt * 64;
        __hip_bfloat16* Kc = &Ks[kt & 1][0];
        __hip_bfloat16* Vc = &Vs[kt & 1][0];
        // stage tile kt into buf[kt&1] (disjoint from in-flight reads of buf[kt&1^1])
#pragma unroll
        for (int i = 0; i < 2; ++i)
            *reinterpret_cast<s16x8*>(Kc + (i * 32 + krow) * 128 + koff) = kreg[i];
#pragma unroll
        for (int i = 0; i < 2; ++i)
            *reinterpret_cast<s16x8*>(Vc + (i * 64 + vrow) * 64 + voff) = vreg[i];
        if (kt < 31) load_tile(kv0 + 64);               // lands under compute (T14)
        int4 mi[4];
#pragma unroll
        for (int ksub = 0; ksub < 4; ++ksub)
            mi[ksub] = *reinterpret_cast<const int4*>(mask + b * S + kv0 + ksub * 16 + hi * 4);
        __syncthreads();                                // buf[kt&1] ready for all

        // P^T = (K Q^T): lane holds P[kv=ksub*16+hi*4+r][q=lo]
        f32x4 sc[4] = {};
        __builtin_amdgcn_s_setprio(1);
#pragma unroll
        for (int ksub = 0; ksub < 4; ++ksub) {
            const int kr = ksub * 16 + lo;
            const int ksw = kr & 7;
#pragma unroll
            for (int kc = 0; kc < 4; ++kc) {
                s16x8 kf = *reinterpret_cast<const s16x8*>(
                    Kc + kr * 128 + (((kc * 4 + hi) ^ ksw) * 8));
                sc[ksub] = __builtin_amdgcn_mfma_f32_16x16x32_bf16(kf, qf[kc], sc[ksub], 0, 0, 0);
            }
        }
        __builtin_amdgcn_s_setprio(0);
        // scale + additive mask bias (per-reg kv index)
#pragma unroll
        for (int ksub = 0; ksub < 4; ++ksub) {
            const int* mw = (const int*)&mi[ksub];
#pragma unroll
            for (int r = 0; r < 4; ++r)
                sc[ksub][r] = sc[ksub][r] * scale + (mw[r] == 0 ? -1e30f : 0.f);
        }
        // tile row-max
        float a0 = fmaxf(fmaxf(sc[0][0], sc[0][1]), fmaxf(sc[0][2], sc[0][3]));
        float a1 = fmaxf(fmaxf(sc[1][0], sc[1][1]), fmaxf(sc[1][2], sc[1][3]));
        float a2 = fmaxf(fmaxf(sc[2][0], sc[2][1]), fmaxf(sc[2][2], sc[2][3]));
        float a3 = fmaxf(fmaxf(sc[3][0], sc[3][1]), fmaxf(sc[3][2], sc[3][3]));
        float mx = fmaxf(fmaxf(a0, a1), fmaxf(a2, a3));
        mx = fmaxf(mx, __shfl_xor(mx, 16));
        mx = fmaxf(mx, __shfl_xor(mx, 32));
        // defer-max: only rescale when some row's max grew past THR=8
        if (__ballot(mx > m_run + 8.f) != 0ull) {
            const float mnew = fmaxf(m_run, mx);
            const float alpha = __expf(m_run - mnew);
            m_run = mnew;
            l_run *= alpha;
            float ar[4];
#pragma unroll
            for (int r = 0; r < 4; ++r) ar[r] = __shfl(alpha, hi * 4 + r);
#pragma unroll
            for (int n = 0; n < 8; ++n)
#pragma unroll
                for (int r = 0; r < 4; ++r) o[n][r] *= ar[r];
        }
        // exp + row-sum (P values bounded by e^8 under defer)
        float s0 = 0.f, s1 = 0.f, s2 = 0.f, s3 = 0.f;
#pragma unroll
        for (int r = 0; r < 4; ++r) {
            sc[0][r] = __expf(sc[0][r] - m_run); s0 += sc[0][r];
            sc[1][r] = __expf(sc[1][r] - m_run); s1 += sc[1][r];
            sc[2][r] = __expf(sc[2][r] - m_run); s2 += sc[2][r];
            sc[3][r] = __expf(sc[3][r] - m_run); s3 += sc[3][r];
        }
        float ssum = (s0 + s1) + (s2 + s3);
        ssum += __shfl_xor(ssum, 16);
        ssum += __shfl_xor(ssum, 32);
        l_run += ssum;
        // P -> LDS: cvt_pk pairs, one b64 per ksub (row q=lo, cols ksub*16+hi*4..+3)
        __hip_bfloat16* pb = &Ps[w][0];
#pragma unroll
        for (int ksub = 0; ksub < 4; ++ksub) {
            unsigned int d0, d1;
            asm("v_cvt_pk_bf16_f32 %0, %1, %2" : "=v"(d0) : "v"(sc[ksub][0]), "v"(sc[ksub][1]));
            asm("v_cvt_pk_bf16_f32 %0, %1, %2" : "=v"(d1) : "v"(sc[ksub][2]), "v"(sc[ksub][3]));
            const int byteoff = lo * 128 + (((ksub * 2 + (hi >> 1)) ^ (lo & 7)) * 16) + (hi & 1) * 8;
            uint2 dd; dd.x = d0; dd.y = d1;
            *reinterpret_cast<uint2*>(reinterpret_cast<char*>(pb) + byteoff) = dd;
        }
        // O += P V
        __builtin_amdgcn_s_setprio(1);
#pragma unroll
        for (int kg = 0; kg < 2; ++kg) {
            s16x8 pa = *reinterpret_cast<const s16x8*>(
                pb + lo * 64 + (((kg * 4 + hi) ^ (lo & 7)) * 8));
#pragma unroll
            for (int n = 0; n < 8; ++n) {
                const int vr = n * 16 + lo;
                s16x8 vb = *reinterpret_cast<const s16x8*>(
                    Vc + vr * 64 + (((kg * 4 + hi) ^ (vr & 7)) * 8));
                o[n] = __builtin_amdgcn_mfma_f32_16x16x32_bf16(pa, vb, o[n], 0, 0, 0);
            }
        }
        __builtin_amdgcn_s_setprio(0);
        // no trailing barrier: next iter writes the other buffer
    }
    // epilogue: attn_out[b*S+s][h*128+d] = o / l   (l lives at lane q)
    float lr[4];
#pragma unroll
    for (int r = 0; r < 4; ++r) lr[r] = __shfl(l_run, hi * 4 + r);
    const int orow = b * S + qt * 128 + w * 16 + (hi * 4);
    const int ocol = h * 128 + lo;
#pragma unroll
    for (int n = 0; n < 8; ++n)
#pragma unroll
        for (int r = 0; r < 4; ++r)
            Oo[(size_t)(orow + r) * 2048 + ocol + n * 16] = __float2bfloat16(o[n][r] / lr[r]);
}

// ---------------- host launch ----------------
extern "C" void kernel_launch(void* const* d_in, const int* in_sizes, int n_in,
                              void* d_out, int out_size, void* d_ws, size_t ws_size,
                              hipStream_t stream) {
    const float* x  = (const float*)d_in[0];
    const int* mask = (const int*)d_in[1];
    const float* Wq = (const float*)d_in[2];
    const float* Wk = (const float*)d_in[3];
    const float* Wv = (const float*)d_in[4];
    const float* Wo = (const float*)d_in[5];
    float* out = (float*)d_out;

    char* ws = (char*)d_ws;
    size_t off = 0;
    auto alloc = [&](size_t bytes) -> void* {
        void* p = ws + off;
        off += (bytes + 255) & ~(size_t)255;
        return p;
    };
    // Distinct regions (~93 MB peak):
    __hip_bfloat16* xb     = (__hip_bfloat16*)alloc(4096ULL * 2048 * 2);   // 16 MB
    __hip_bfloat16* wqkv_t = (__hip_bfloat16*)alloc(3072ULL * 2048 * 2);   // 12 MB
    __hip_bfloat16* wo_t   = (__hip_bfloat16*)alloc(2048ULL * 2048 * 2);   // 8 MB
    float*          qkv    = (float*)alloc(4096ULL * 3072 * 4);            // 48 MB
    __hip_bfloat16* Kr     = (__hip_bfloat16*)alloc(2ULL * 4 * 2048 * 128 * 2);  // 4 MB
    __hip_bfloat16* Vt     = (__hip_bfloat16*)alloc(2ULL * 4 * 2048 * 128 * 2);  // 4 MB
    float*          cosT   = (float*)alloc(2048ULL * 64 * 4);
    float*          sinT   = (float*)alloc(2048ULL * 64 * 4);
    // Aliases (regions dead by the time these are written):
    __hip_bfloat16* Qr    = xb;                   // xb dead after QKV GEMM; Qr written after
    __hip_bfloat16* attno = (__hip_bfloat16*)qkv; // qkv dead after rope_scatter; attno written after

    rope_tables<<<dim3(2048), dim3(64), 0, stream>>>(cosT, sinT);
    cast_f32_bf16<<<dim3(8192), dim3(256), 0, stream>>>(x, xb, 2097152);
    transpose_cast<<<dim3(64, 64), dim3(32, 8), 0, stream>>>(Wq, wqkv_t, 2048, 2048);
    transpose_cast<<<dim3(16, 64), dim3(32, 8), 0, stream>>>(Wk, wqkv_t + 2048ULL * 2048, 2048, 512);
    transpose_cast<<<dim3(16, 64), dim3(32, 8), 0, stream>>>(Wv, wqkv_t + 2560ULL * 2048, 2048, 512);
    transpose_cast<<<dim3(64, 64), dim3(32, 8), 0, stream>>>(Wo, wo_t, 2048, 2048);

    gemm_bt_f32<<<dim3(24, 32), dim3(256), 0, stream>>>(xb, wqkv_t, qkv, 4096, 3072, 2048);
    rope_scatter<<<dim3(12, 4096), dim3(256), 0, stream>>>(qkv, cosT, sinT, Qr, Kr, Vt);
    attn_kernel<<<dim3(16, 32), dim3(512), 0, stream>>>(Qr, Kr, Vt, mask, attno);
    gemm_bt_f32<<<dim3(16, 32), dim3(256), 0, stream>>>(attno, wo_t, out, 4096, 2048, 2048);
}

// Round 7
// 263.749 us; speedup vs baseline: 1.9568x; 1.0872x over previous
//
#include <hip/hip_runtime.h>
#include <hip/hip_bf16.h>

typedef __attribute__((ext_vector_type(4))) float f32x4;
typedef __attribute__((ext_vector_type(8))) short s16x8;
typedef __attribute__((ext_vector_type(4))) short s16x4;

// ---------------- RoPE tables (tiny, double precision) ----------------
__global__ void rope_tables(float* __restrict__ cosT, float* __restrict__ sinT) {
    const int s = blockIdx.x, j = threadIdx.x;          // s in [0,2048), j in [0,64)
    const double inv = pow(10000.0, -(double)j / 64.0);
    const double f = (double)s * inv;
    cosT[s * 64 + j] = (float)cos(f);
    sinT[s * 64 + j] = (float)sin(f);
}

// ---------------- cast fp32 -> bf16 (vectorized) ----------------
__global__ __launch_bounds__(256)
void cast_f32_bf16(const float* __restrict__ src, __hip_bfloat16* __restrict__ dst, int n4) {
    const int i = blockIdx.x * 256 + threadIdx.x;
    if (i < n4) {
        f32x4 v = *reinterpret_cast<const f32x4*>(src + (size_t)i * 4);
        union { s16x4 v4; __hip_bfloat16 h[4]; } u;
#pragma unroll
        for (int j = 0; j < 4; ++j) u.h[j] = __float2bfloat16(v[j]);
        *reinterpret_cast<s16x4*>(dst + (size_t)i * 4) = u.v4;
    }
}

// ---------------- tiled transpose + cast: dst[c][r] = (bf16)src[r][c] ----------------
__global__ __launch_bounds__(256)
void transpose_cast(const float* __restrict__ src, __hip_bfloat16* __restrict__ dst,
                    int R, int C) {
    __shared__ __align__(16) float t[32][33];
    const int tx = threadIdx.x, ty = threadIdx.y;       // (32, 8)
    const int r0 = blockIdx.y * 32, c0 = blockIdx.x * 32;
#pragma unroll
    for (int i = 0; i < 32; i += 8)
        t[ty + i][tx] = src[(size_t)(r0 + ty + i) * C + c0 + tx];
    __syncthreads();
#pragma unroll
    for (int i = 0; i < 32; i += 8)
        dst[(size_t)(c0 + ty + i) * R + r0 + tx] = __float2bfloat16(t[tx][ty + i]);
}

// ---------------- 256-row-tile GEMM with counted-vmcnt 4-slot pipeline (T4) ----------
// C(f32)[M][N] = A[M][K] * Bt[N][K]^T.  8 waves (2M x 4N), per-wave 128 x (NI*16).
// LDS: 4-slot ring, each slot = A[256][32] + B[256][32] bf16 (128 KiB total).
// Stage tile t+3 (global_load_lds, pre-swizzled global source chunk^row&3) while
// computing tile t; ONE raw s_barrier per tile; steady-state vmcnt(8|6) keeps 2
// tiles of loads in flight ACROSS the barrier (never drain to 0 mid-loop).
// Safety: lgkmcnt(0) before each barrier => slot reads complete before the
// overwrite-issue (>= 1 barrier later); per-wave vmcnt wait before barrier =>
// collective landing of tile t before any ds_read of it.
template<int NI>   // NI = per-wave N fragments: 4 -> BN=256, 2 -> BN=128
__global__ __launch_bounds__(512, 2)
void gemm256_bt_f32(const __hip_bfloat16* __restrict__ A,
                    const __hip_bfloat16* __restrict__ Bt,
                    float* __restrict__ C, int M, int N, int K) {
    constexpr int NB = NI / 2;                          // B-stage loads per thread
    __shared__ __align__(16) __hip_bfloat16 sm[4][2][8192];
    const int tid = threadIdx.x;
    const int l = tid & 63, w = tid >> 6;               // 8 waves
    const int lo = l & 15, hi = l >> 4;
    const int wm = w >> 2, wn = w & 3;
    const int row0 = blockIdx.y * 256;
    const int col0 = blockIdx.x * (NI * 64);
    const int nk = K >> 5;

    f32x4 acc[8][NI];
#pragma unroll
    for (int mi = 0; mi < 8; ++mi)
#pragma unroll
        for (int ni = 0; ni < NI; ++ni) acc[mi][ni] = f32x4{0.f, 0.f, 0.f, 0.f};

    auto stage = [&](int kt) {
        const int s = kt & 3, k0 = kt << 5;
#pragma unroll
        for (int i = 0; i < 2; ++i) {                   // A: 256 rows x 4 chunks
            const int c = i * 512 + tid;
            const int r = c >> 2, sw = ((c & 3) ^ (r & 3)) * 8;
            __builtin_amdgcn_global_load_lds(
                (const __attribute__((address_space(1))) void*)(A + (size_t)(row0 + r) * K + k0 + sw),
                (__attribute__((address_space(3))) void*)(&sm[s][0][c * 8]), 16, 0, 0);
        }
#pragma unroll
        for (int i = 0; i < NB; ++i) {                  // B: NI*64 rows x 4 chunks
            const int c = i * 512 + tid;
            const int r = c >> 2, sw = ((c & 3) ^ (r & 3)) * 8;
            __builtin_amdgcn_global_load_lds(
                (const __attribute__((address_space(1))) void*)(Bt + (size_t)(col0 + r) * K + k0 + sw),
                (__attribute__((address_space(3))) void*)(&sm[s][1][c * 8]), 16, 0, 0);
        }
    };

    stage(0); stage(1); stage(2);                       // 3 tiles ahead
    for (int kt = 0; kt < nk; ++kt) {
        const int s = kt & 3;
        // counted wait: tile kt landed; keep later tiles' loads in flight
        if (kt < nk - 2) {
            if constexpr (NI == 4) asm volatile("s_waitcnt vmcnt(8)" ::: "memory");
            else                   asm volatile("s_waitcnt vmcnt(6)" ::: "memory");
        } else if (kt == nk - 2) {
            if constexpr (NI == 4) asm volatile("s_waitcnt vmcnt(4)" ::: "memory");
            else                   asm volatile("s_waitcnt vmcnt(3)" ::: "memory");
        } else {
            asm volatile("s_waitcnt vmcnt(0)" ::: "memory");
        }
        asm volatile("s_waitcnt lgkmcnt(0)" ::: "memory");  // slot reads of kt-1 done
        asm volatile("s_barrier" ::: "memory");             // no compiler drain added
        if (kt + 3 < nk) stage(kt + 3);                     // into slot (kt-1)&3: safe

        s16x8 af[8], bf[NI];
#pragma unroll
        for (int mi = 0; mi < 8; ++mi)
            af[mi] = *reinterpret_cast<const s16x8*>(
                &sm[s][0][(wm * 128 + mi * 16 + lo) * 32 + ((hi ^ (lo & 3)) * 8)]);
#pragma unroll
        for (int ni = 0; ni < NI; ++ni)
            bf[ni] = *reinterpret_cast<const s16x8*>(
                &sm[s][1][(wn * NI * 16 + ni * 16 + lo) * 32 + ((hi ^ (lo & 3)) * 8)]);
        __builtin_amdgcn_s_setprio(1);
#pragma unroll
        for (int mi = 0; mi < 8; ++mi)
#pragma unroll
            for (int ni = 0; ni < NI; ++ni)
                acc[mi][ni] = __builtin_amdgcn_mfma_f32_16x16x32_bf16(af[mi], bf[ni], acc[mi][ni], 0, 0, 0);
        __builtin_amdgcn_s_setprio(0);
    }
    const int rbase = row0 + wm * 128 + hi * 4;
    const int cbase = col0 + wn * NI * 16 + lo;
#pragma unroll
    for (int mi = 0; mi < 8; ++mi)
#pragma unroll
        for (int ni = 0; ni < NI; ++ni)
#pragma unroll
            for (int r = 0; r < 4; ++r)
                C[(size_t)(rbase + mi * 16 + r) * N + cbase + ni * 16] = acc[mi][ni][r];
}

// ---------------- RoPE + scatter into attention layouts ----------------
// qkv: f32 [4096][3072] (Q 0..2047 | K 2048..2559 | V 2560..3071)
// Qr: bf16 [2][16][2048][128], Kr: bf16 [2][4][2048][128], Vt: bf16 [2][4][128][2048]
__global__ __launch_bounds__(256)
void rope_scatter(const float* __restrict__ qkv,
                  const float* __restrict__ cosT, const float* __restrict__ sinT,
                  __hip_bfloat16* __restrict__ Qr, __hip_bfloat16* __restrict__ Kr,
                  __hip_bfloat16* __restrict__ Vt) {
    const int m = blockIdx.y;                           // token row, 0..4095
    const int col = blockIdx.x * 256 + threadIdx.x;     // 0..3071
    const int b = m >> 11, s = m & 2047;
    const float v = qkv[(size_t)m * 3072 + col];
    if (col < 2560) {                                   // Q or K: apply RoPE
        const int d = col & 127;                        // head-aligned regions
        const int j = d & 63;
        const float c = cosT[s * 64 + j], sn = sinT[s * 64 + j];
        const float partner = qkv[(size_t)m * 3072 + (col ^ 64)];
        const float rot = (d < 64) ? -partner : partner;
        const float o = v * c + rot * sn;
        if (col < 2048) {
            const int hh = col >> 7;
            Qr[((size_t)(b * 16 + hh) * 2048 + s) * 128 + d] = __float2bfloat16(o);
        } else {
            const int hh = (col - 2048) >> 7;
            Kr[((size_t)(b * 4 + hh) * 2048 + s) * 128 + d] = __float2bfloat16(o);
        }
    } else {                                            // V: transpose-scatter
        const int cc = col - 2560;
        const int hh = cc >> 7, d = cc & 127;
        Vt[((size_t)(b * 4 + hh) * 128 + d) * 2048 + s] = __float2bfloat16(v);
    }
}

// ---------------- flash attention: 128 Q-rows/block (8 waves), KV tiles of 64 ----------------
__global__ __launch_bounds__(512, 4)
void attn_kernel(const __hip_bfloat16* __restrict__ Qr,
                 const __hip_bfloat16* __restrict__ Kr,
                 const __hip_bfloat16* __restrict__ Vt,
                 const int* __restrict__ mask,
                 __hip_bfloat16* __restrict__ Oo) {
    const int S = 2048;
    const int qt = blockIdx.x;                          // 0..15 (128 q-rows per block)
    const int bh = blockIdx.y;                          // 0..31
    const int b = bh >> 4, h = bh & 15, kvh = h >> 2;
    const int tid = threadIdx.x;
    const int l = tid & 63, w = tid >> 6;               // 8 waves
    const int lo = l & 15, hi = l >> 4;
    __shared__ __align__(16) __hip_bfloat16 Ks[2][64 * 128];   // [kv][d], swizzled
    __shared__ __align__(16) __hip_bfloat16 Vs[2][128 * 64];   // [d][kv], swizzled
    __shared__ __align__(16) __hip_bfloat16 Ps[8][16 * 64];    // per-wave [q][kv], swizzled

    const __hip_bfloat16* Qb = Qr + (size_t)(b * 16 + h) * S * 128;
    const __hip_bfloat16* Kb = Kr + (size_t)(b * 4 + kvh) * S * 128;
    const __hip_bfloat16* Vb = Vt + (size_t)(b * 4 + kvh) * 128 * S;

    // Q fragments in registers: wave owns rows qt*128 + w*16 .. +15
    const int qrow = qt * 128 + w * 16 + lo;
    s16x8 qf[4];
#pragma unroll
    for (int kc = 0; kc < 4; ++kc)
        qf[kc] = *reinterpret_cast<const s16x8*>(Qb + (size_t)qrow * 128 + kc * 32 + hi * 8);

    float m_run = -1e30f, l_run = 0.f;                  // this lane's q-row is lo
    f32x4 o[8];
#pragma unroll
    for (int n = 0; n < 8; ++n) o[n] = f32x4{0.f, 0.f, 0.f, 0.f};
    const float scale = 0.08838834764831845f;           // 1/sqrt(128)

    // --- staging geometry: 512 threads stage K (64x16 chunks) and V (128x8 chunks), 2 each ---
    const int krow = tid >> 4, kc8 = tid & 15;          // krow 0..31 (+i*32)
    const int koff = (kc8 ^ (krow & 7)) * 8;            // 32 % 8 == 0 -> same swz both i
    const int vrow = tid >> 3, vc8 = tid & 7;           // vrow 0..63 (+i*64)
    const int voff = (vc8 ^ (vrow & 7)) * 8;

    s16x8 kreg[2], vreg[2];
    auto load_tile = [&](int kv0) {
#pragma unroll
        for (int i = 0; i < 2; ++i)
            kreg[i] = *reinterpret_cast<const s16x8*>(
                Kb + (size_t)(kv0 + i * 32 + krow) * 128 + kc8 * 8);
#pragma unroll
        for (int i = 0; i < 2; ++i)
            vreg[i] = *reinterpret_cast<const s16x8*>(
                Vb + (size_t)(i * 64 + vrow) * S + kv0 + vc8 * 8);
    };

    load_tile(0);
    for (int kt = 0; kt < 32; ++kt) {
        const int kv0 = kt * 64;
        __hip_bfloat16* Kc = &Ks[kt & 1][0];
        __hip_bfloat16* Vc = &Vs[kt & 1][0];
        // stage tile kt into buf[kt&1] (disjoint from in-flight reads of buf[kt&1^1])
#pragma unroll
        for (int i = 0; i < 2; ++i)
            *reinterpret_cast<s16x8*>(Kc + (i * 32 + krow) * 128 + koff) = kreg[i];
#pragma unroll
        for (int i = 0; i < 2; ++i)
            *reinterpret_cast<s16x8*>(Vc + (i * 64 + vrow) * 64 + voff) = vreg[i];
        if (kt < 31) load_tile(kv0 + 64);               // lands under compute (T14)
        int4 mi[4];
#pragma unroll
        for (int ksub = 0; ksub < 4; ++ksub)
            mi[ksub] = *reinterpret_cast<const int4*>(mask + b * S + kv0 + ksub * 16 + hi * 4);
        __syncthreads();                                // buf[kt&1] ready for all

        // P^T = (K Q^T): lane holds P[kv=ksub*16+hi*4+r][q=lo]
        f32x4 sc[4] = {};
        __builtin_amdgcn_s_setprio(1);
#pragma unroll
        for (int ksub = 0; ksub < 4; ++ksub) {
            const int kr = ksub * 16 + lo;
            const int ksw = kr & 7;
#pragma unroll
            for (int kc = 0; kc < 4; ++kc) {
                s16x8 kf = *reinterpret_cast<const s16x8*>(
                    Kc + kr * 128 + (((kc * 4 + hi) ^ ksw) * 8));
                sc[ksub] = __builtin_amdgcn_mfma_f32_16x16x32_bf16(kf, qf[kc], sc[ksub], 0, 0, 0);
            }
        }
        __builtin_amdgcn_s_setprio(0);
        // scale + additive mask bias (per-reg kv index)
#pragma unroll
        for (int ksub = 0; ksub < 4; ++ksub) {
            const int* mw = (const int*)&mi[ksub];
#pragma unroll
            for (int r = 0; r < 4; ++r)
                sc[ksub][r] = sc[ksub][r] * scale + (mw[r] == 0 ? -1e30f : 0.f);
        }
        // tile row-max
        float a0 = fmaxf(fmaxf(sc[0][0], sc[0][1]), fmaxf(sc[0][2], sc[0][3]));
        float a1 = fmaxf(fmaxf(sc[1][0], sc[1][1]), fmaxf(sc[1][2], sc[1][3]));
        float a2 = fmaxf(fmaxf(sc[2][0], sc[2][1]), fmaxf(sc[2][2], sc[2][3]));
        float a3 = fmaxf(fmaxf(sc[3][0], sc[3][1]), fmaxf(sc[3][2], sc[3][3]));
        float mx = fmaxf(fmaxf(a0, a1), fmaxf(a2, a3));
        mx = fmaxf(mx, __shfl_xor(mx, 16));
        mx = fmaxf(mx, __shfl_xor(mx, 32));
        // defer-max: only rescale when some row's max grew past THR=8
        if (__ballot(mx > m_run + 8.f) != 0ull) {
            const float mnew = fmaxf(m_run, mx);
            const float alpha = __expf(m_run - mnew);
            m_run = mnew;
            l_run *= alpha;
            float ar[4];
#pragma unroll
            for (int r = 0; r < 4; ++r) ar[r] = __shfl(alpha, hi * 4 + r);
#pragma unroll
            for (int n = 0; n < 8; ++n)
#pragma unroll
                for (int r = 0; r < 4; ++r) o[n][r] *= ar[r];
        }
        // exp + row-sum (P values bounded by e^8 under defer)
        float s0 = 0.f, s1 = 0.f, s2 = 0.f, s3 = 0.f;
#pragma unroll
        for (int r = 0; r < 4; ++r) {
            sc[0][r] = __expf(sc[0][r] - m_run); s0 += sc[0][r];
            sc[1][r] = __expf(sc[1][r] - m_run); s1 += sc[1][r];
            sc[2][r] = __expf(sc[2][r] - m_run); s2 += sc[2][r];
            sc[3][r] = __expf(sc[3][r] - m_run); s3 += sc[3][r];
        }
        float ssum = (s0 + s1) + (s2 + s3);
        ssum += __shfl_xor(ssum, 16);
        ssum += __shfl_xor(ssum, 32);
        l_run += ssum;
        // P -> LDS: cvt_pk pairs, one b64 per ksub (row q=lo, cols ksub*16+hi*4..+3)
        __hip_bfloat16* pb = &Ps[w][0];
#pragma unroll
        for (int ksub = 0; ksub < 4; ++ksub) {
            unsigned int d0, d1;
            asm("v_cvt_pk_bf16_f32 %0, %1, %2" : "=v"(d0) : "v"(sc[ksub][0]), "v"(sc[ksub][1]));
            asm("v_cvt_pk_bf16_f32 %0, %1, %2" : "=v"(d1) : "v"(sc[ksub][2]), "v"(sc[ksub][3]));
            const int byteoff = lo * 128 + (((ksub * 2 + (hi >> 1)) ^ (lo & 7)) * 16) + (hi & 1) * 8;
            uint2 dd; dd.x = d0; dd.y = d1;
            *reinterpret_cast<uint2*>(reinterpret_cast<char*>(pb) + byteoff) = dd;
        }
        // O += P V
        __builtin_amdgcn_s_setprio(1);
#pragma unroll
        for (int kg = 0; kg < 2; ++kg) {
            s16x8 pa = *reinterpret_cast<const s16x8*>(
                pb + lo * 64 + (((kg * 4 + hi) ^ (lo & 7)) * 8));
#pragma unroll
            for (int n = 0; n < 8; ++n) {
                const int vr = n * 16 + lo;
                s16x8 vb = *reinterpret_cast<const s16x8*>(
                    Vc + vr * 64 + (((kg * 4 + hi) ^ (vr & 7)) * 8));
                o[n] = __builtin_amdgcn_mfma_f32_16x16x32_bf16(pa, vb, o[n], 0, 0, 0);
            }
        }
        __builtin_amdgcn_s_setprio(0);
        // no trailing barrier: next iter writes the other buffer
    }
    // epilogue: attn_out[b*S+s][h*128+d] = o / l   (l lives at lane q)
    float lr[4];
#pragma unroll
    for (int r = 0; r < 4; ++r) lr[r] = __shfl(l_run, hi * 4 + r);
    const int orow = b * S + qt * 128 + w * 16 + (hi * 4);
    const int ocol = h * 128 + lo;
#pragma unroll
    for (int n = 0; n < 8; ++n)
#pragma unroll
        for (int r = 0; r < 4; ++r)
            Oo[(size_t)(orow + r) * 2048 + ocol + n * 16] = __float2bfloat16(o[n][r] / lr[r]);
}

// ---------------- host launch ----------------
extern "C" void kernel_launch(void* const* d_in, const int* in_sizes, int n_in,
                              void* d_out, int out_size, void* d_ws, size_t ws_size,
                              hipStream_t stream) {
    const float* x  = (const float*)d_in[0];
    const int* mask = (const int*)d_in[1];
    const float* Wq = (const float*)d_in[2];
    const float* Wk = (const float*)d_in[3];
    const float* Wv = (const float*)d_in[4];
    const float* Wo = (const float*)d_in[5];
    float* out = (float*)d_out;

    char* ws = (char*)d_ws;
    size_t off = 0;
    auto alloc = [&](size_t bytes) -> void* {
        void* p = ws + off;
        off += (bytes + 255) & ~(size_t)255;
        return p;
    };
    // Distinct regions (~93 MB peak):
    __hip_bfloat16* xb     = (__hip_bfloat16*)alloc(4096ULL * 2048 * 2);   // 16 MB
    __hip_bfloat16* wqkv_t = (__hip_bfloat16*)alloc(3072ULL * 2048 * 2);   // 12 MB
    __hip_bfloat16* wo_t   = (__hip_bfloat16*)alloc(2048ULL * 2048 * 2);   // 8 MB
    float*          qkv    = (float*)alloc(4096ULL * 3072 * 4);            // 48 MB
    __hip_bfloat16* Kr     = (__hip_bfloat16*)alloc(2ULL * 4 * 2048 * 128 * 2);  // 4 MB
    __hip_bfloat16* Vt     = (__hip_bfloat16*)alloc(2ULL * 4 * 2048 * 128 * 2);  // 4 MB
    float*          cosT   = (float*)alloc(2048ULL * 64 * 4);
    float*          sinT   = (float*)alloc(2048ULL * 64 * 4);
    // Aliases (regions dead by the time these are written):
    __hip_bfloat16* Qr    = xb;                   // xb dead after QKV GEMM; Qr written after
    __hip_bfloat16* attno = (__hip_bfloat16*)qkv; // qkv dead after rope_scatter; attno written after

    rope_tables<<<dim3(2048), dim3(64), 0, stream>>>(cosT, sinT);
    cast_f32_bf16<<<dim3(8192), dim3(256), 0, stream>>>(x, xb, 2097152);
    transpose_cast<<<dim3(64, 64), dim3(32, 8), 0, stream>>>(Wq, wqkv_t, 2048, 2048);
    transpose_cast<<<dim3(16, 64), dim3(32, 8), 0, stream>>>(Wk, wqkv_t + 2048ULL * 2048, 2048, 512);
    transpose_cast<<<dim3(16, 64), dim3(32, 8), 0, stream>>>(Wv, wqkv_t + 2560ULL * 2048, 2048, 512);
    transpose_cast<<<dim3(64, 64), dim3(32, 8), 0, stream>>>(Wo, wo_t, 2048, 2048);

    // QKV: 256x256 tiles -> grid (3072/256, 4096/256) = (12,16)
    gemm256_bt_f32<4><<<dim3(12, 16), dim3(512), 0, stream>>>(xb, wqkv_t, qkv, 4096, 3072, 2048);
    rope_scatter<<<dim3(12, 4096), dim3(256), 0, stream>>>(qkv, cosT, sinT, Qr, Kr, Vt);
    attn_kernel<<<dim3(16, 32), dim3(512), 0, stream>>>(Qr, Kr, Vt, mask, attno);
    // Wo: 256x128 tiles -> grid (2048/128, 4096/256) = (16,16) = 256 blocks (full chip)
    gemm256_bt_f32<2><<<dim3(16, 16), dim3(512), 0, stream>>>(attno, wo_t, out, 4096, 2048, 2048);
}

// Round 8
// 250.844 us; speedup vs baseline: 2.0575x; 1.0514x over previous
//
#include <hip/hip_runtime.h>
#include <hip/hip_bf16.h>

typedef __attribute__((ext_vector_type(4))) float f32x4;
typedef __attribute__((ext_vector_type(8))) short s16x8;
typedef __attribute__((ext_vector_type(4))) short s16x4;

__device__ __forceinline__ float fexp2(float x) {   // 2^x (hw interlocked on CDNA)
    float y; asm("v_exp_f32 %0, %1" : "=v"(y) : "v"(x)); return y;
}

// ---------------- RoPE tables (tiny, double precision) ----------------
__global__ void rope_tables(float* __restrict__ cosT, float* __restrict__ sinT) {
    const int s = blockIdx.x, j = threadIdx.x;          // s in [0,2048), j in [0,64)
    const double inv = pow(10000.0, -(double)j / 64.0);
    const double f = (double)s * inv;
    cosT[s * 64 + j] = (float)cos(f);
    sinT[s * 64 + j] = (float)sin(f);
}

// ---------------- mask -> additive float bias ----------------
__global__ void mask_bias(const int* __restrict__ mask, float* __restrict__ mb, int n) {
    const int i = blockIdx.x * 256 + threadIdx.x;
    if (i < n) mb[i] = (mask[i] == 0) ? -1e30f : 0.f;
}

// ---------------- cast fp32 -> bf16 (vectorized) ----------------
__global__ __launch_bounds__(256)
void cast_f32_bf16(const float* __restrict__ src, __hip_bfloat16* __restrict__ dst, int n4) {
    const int i = blockIdx.x * 256 + threadIdx.x;
    if (i < n4) {
        f32x4 v = *reinterpret_cast<const f32x4*>(src + (size_t)i * 4);
        union { s16x4 v4; __hip_bfloat16 h[4]; } u;
#pragma unroll
        for (int j = 0; j < 4; ++j) u.h[j] = __float2bfloat16(v[j]);
        *reinterpret_cast<s16x4*>(dst + (size_t)i * 4) = u.v4;
    }
}

// ---------------- tiled transpose + cast: dst[c][r] = (bf16)src[r][c] ----------------
__global__ __launch_bounds__(256)
void transpose_cast(const float* __restrict__ src, __hip_bfloat16* __restrict__ dst,
                    int R, int C) {
    __shared__ __align__(16) float t[32][33];
    const int tx = threadIdx.x, ty = threadIdx.y;       // (32, 8)
    const int r0 = blockIdx.y * 32, c0 = blockIdx.x * 32;
#pragma unroll
    for (int i = 0; i < 32; i += 8)
        t[ty + i][tx] = src[(size_t)(r0 + ty + i) * C + c0 + tx];
    __syncthreads();
#pragma unroll
    for (int i = 0; i < 32; i += 8)
        dst[(size_t)(c0 + ty + i) * R + r0 + tx] = __float2bfloat16(t[tx][ty + i]);
}

// ---------------- V slice of qkv -> Vt[b][hh][d][s] (LDS-tiled transpose) ----------------
__global__ __launch_bounds__(256)
void vt_transpose(const float* __restrict__ qkv, __hip_bfloat16* __restrict__ Vt) {
    __shared__ __align__(16) float t[32][33];
    const int tx = threadIdx.x, ty = threadIdx.y;       // (32, 8)
    const int s0 = blockIdx.x * 32, d0 = blockIdx.y * 32;
    const int bh = blockIdx.z, b = bh >> 2, hh = bh & 3;
#pragma unroll
    for (int i = 0; i < 32; i += 8)
        t[ty + i][tx] = qkv[(size_t)(b * 2048 + s0 + ty + i) * 3072 + 2560 + hh * 128 + d0 + tx];
    __syncthreads();
#pragma unroll
    for (int i = 0; i < 32; i += 8)
        Vt[((size_t)(bh * 128) + d0 + ty + i) * 2048 + s0 + tx] = __float2bfloat16(t[tx][ty + i]);
}

// ---------------- 256-row-tile GEMM with counted-vmcnt 4-slot pipeline (T4) ----------
template<int NI>   // NI = per-wave N fragments: 4 -> BN=256, 2 -> BN=128
__global__ __launch_bounds__(512, 2)
void gemm256_bt_f32(const __hip_bfloat16* __restrict__ A,
                    const __hip_bfloat16* __restrict__ Bt,
                    float* __restrict__ C, int M, int N, int K) {
    constexpr int NB = NI / 2;                          // B-stage loads per thread
    __shared__ __align__(16) __hip_bfloat16 sm[4][2][8192];
    const int tid = threadIdx.x;
    const int l = tid & 63, w = tid >> 6;               // 8 waves
    const int lo = l & 15, hi = l >> 4;
    const int wm = w >> 2, wn = w & 3;
    const int row0 = blockIdx.y * 256;
    const int col0 = blockIdx.x * (NI * 64);
    const int nk = K >> 5;

    f32x4 acc[8][NI];
#pragma unroll
    for (int mi = 0; mi < 8; ++mi)
#pragma unroll
        for (int ni = 0; ni < NI; ++ni) acc[mi][ni] = f32x4{0.f, 0.f, 0.f, 0.f};

    auto stage = [&](int kt) {
        const int s = kt & 3, k0 = kt << 5;
#pragma unroll
        for (int i = 0; i < 2; ++i) {                   // A: 256 rows x 4 chunks
            const int c = i * 512 + tid;
            const int r = c >> 2, sw = ((c & 3) ^ (r & 3)) * 8;
            __builtin_amdgcn_global_load_lds(
                (const __attribute__((address_space(1))) void*)(A + (size_t)(row0 + r) * K + k0 + sw),
                (__attribute__((address_space(3))) void*)(&sm[s][0][c * 8]), 16, 0, 0);
        }
#pragma unroll
        for (int i = 0; i < NB; ++i) {                  // B: NI*64 rows x 4 chunks
            const int c = i * 512 + tid;
            const int r = c >> 2, sw = ((c & 3) ^ (r & 3)) * 8;
            __builtin_amdgcn_global_load_lds(
                (const __attribute__((address_space(1))) void*)(Bt + (size_t)(col0 + r) * K + k0 + sw),
                (__attribute__((address_space(3))) void*)(&sm[s][1][c * 8]), 16, 0, 0);
        }
    };

    stage(0); stage(1); stage(2);                       // 3 tiles ahead
    for (int kt = 0; kt < nk; ++kt) {
        const int s = kt & 3;
        if (kt < nk - 2) {
            if constexpr (NI == 4) asm volatile("s_waitcnt vmcnt(8)" ::: "memory");
            else                   asm volatile("s_waitcnt vmcnt(6)" ::: "memory");
        } else if (kt == nk - 2) {
            if constexpr (NI == 4) asm volatile("s_waitcnt vmcnt(4)" ::: "memory");
            else                   asm volatile("s_waitcnt vmcnt(3)" ::: "memory");
        } else {
            asm volatile("s_waitcnt vmcnt(0)" ::: "memory");
        }
        asm volatile("s_waitcnt lgkmcnt(0)" ::: "memory");  // slot reads of kt-1 done
        asm volatile("s_barrier" ::: "memory");             // no compiler drain added
        if (kt + 3 < nk) stage(kt + 3);                     // into slot (kt-1)&3: safe

        s16x8 af[8], bf[NI];
#pragma unroll
        for (int mi = 0; mi < 8; ++mi)
            af[mi] = *reinterpret_cast<const s16x8*>(
                &sm[s][0][(wm * 128 + mi * 16 + lo) * 32 + ((hi ^ (lo & 3)) * 8)]);
#pragma unroll
        for (int ni = 0; ni < NI; ++ni)
            bf[ni] = *reinterpret_cast<const s16x8*>(
                &sm[s][1][(wn * NI * 16 + ni * 16 + lo) * 32 + ((hi ^ (lo & 3)) * 8)]);
        __builtin_amdgcn_s_setprio(1);
#pragma unroll
        for (int mi = 0; mi < 8; ++mi)
#pragma unroll
            for (int ni = 0; ni < NI; ++ni)
                acc[mi][ni] = __builtin_amdgcn_mfma_f32_16x16x32_bf16(af[mi], bf[ni], acc[mi][ni], 0, 0, 0);
        __builtin_amdgcn_s_setprio(0);
    }
    const int rbase = row0 + wm * 128 + hi * 4;
    const int cbase = col0 + wn * NI * 16 + lo;
#pragma unroll
    for (int mi = 0; mi < 8; ++mi)
#pragma unroll
        for (int ni = 0; ni < NI; ++ni)
#pragma unroll
            for (int r = 0; r < 4; ++r)
                C[(size_t)(rbase + mi * 16 + r) * N + cbase + ni * 16] = acc[mi][ni][r];
}

// ---------------- RoPE + scatter (Q/K only, float4-vectorized) ----------------
// qkv: f32 [4096][3072]; Qr: bf16 [2][16][2048][128], Kr: bf16 [2][4][2048][128]
__global__ __launch_bounds__(256)
void rope_scatter(const float* __restrict__ qkv,
                  const float* __restrict__ cosT, const float* __restrict__ sinT,
                  __hip_bfloat16* __restrict__ Qr, __hip_bfloat16* __restrict__ Kr) {
    const int m = blockIdx.y;                           // token row, 0..4095
    const int col4 = blockIdx.x * 256 + threadIdx.x;    // 0..639
    if (col4 >= 640) return;
    const int col = col4 * 4;
    const int b = m >> 11, s = m & 2047;
    const int d = col & 127;                            // 4-aligned
    const int j = d & 63;
    const f32x4 v = *reinterpret_cast<const f32x4*>(qkv + (size_t)m * 3072 + col);
    const f32x4 p = *reinterpret_cast<const f32x4*>(qkv + (size_t)m * 3072 + (col ^ 64));
    const f32x4 c4 = *reinterpret_cast<const f32x4*>(cosT + s * 64 + j);
    const f32x4 s4 = *reinterpret_cast<const f32x4*>(sinT + s * 64 + j);
    const float sgn = (d < 64) ? -1.f : 1.f;
    union { s16x4 v4; __hip_bfloat16 h[4]; } u;
#pragma unroll
    for (int i = 0; i < 4; ++i)
        u.h[i] = __float2bfloat16(v[i] * c4[i] + sgn * p[i] * s4[i]);
    if (col < 2048) {
        const int hh = col >> 7;
        *reinterpret_cast<s16x4*>(&Qr[((size_t)(b * 16 + hh) * 2048 + s) * 128 + d]) = u.v4;
    } else {
        const int hh = (col - 2048) >> 7;
        *reinterpret_cast<s16x4*>(&Kr[((size_t)(b * 4 + hh) * 2048 + s) * 128 + d]) = u.v4;
    }
}

// ---------------- flash attention: 128 Q-rows/block (8 waves), KV tiles of 64 ----------------
// Swapped QK^T (T12) + in-register exp2-domain softmax + defer-max (T13) +
// double-buffered K/V with ONE barrier per tile. Manual x2 unroll makes LDS
// buffer bases compile-time constants -> swizzled offsets are loop-invariant.
__global__ __launch_bounds__(512, 4)
void attn_kernel(const __hip_bfloat16* __restrict__ Qr,
                 const __hip_bfloat16* __restrict__ Kr,
                 const __hip_bfloat16* __restrict__ Vt,
                 const float* __restrict__ maskb,
                 __hip_bfloat16* __restrict__ Oo) {
    const int S = 2048;
    const int qt = blockIdx.x;                          // 0..15 (128 q-rows per block)
    const int bh = blockIdx.y;                          // 0..31
    const int b = bh >> 4, h = bh & 15, kvh = h >> 2;
    const int tid = threadIdx.x;
    const int l = tid & 63, w = tid >> 6;               // 8 waves
    const int lo = l & 15, hi = l >> 4;
    __shared__ __align__(16) __hip_bfloat16 Ks[2][64 * 128];   // [kv][d], swizzled
    __shared__ __align__(16) __hip_bfloat16 Vs[2][128 * 64];   // [d][kv], swizzled
    __shared__ __align__(16) __hip_bfloat16 Ps[8][16 * 64];    // per-wave [q][kv], swizzled

    const __hip_bfloat16* Qb = Qr + (size_t)(b * 16 + h) * S * 128;
    const __hip_bfloat16* Kb = Kr + (size_t)(b * 4 + kvh) * S * 128;
    const __hip_bfloat16* Vb = Vt + (size_t)(b * 4 + kvh) * 128 * S;
    const float* mrow = maskb + b * S;

    // Q fragments in registers: wave owns rows qt*128 + w*16 .. +15
    const int qrow = qt * 128 + w * 16 + lo;
    s16x8 qf[4];
#pragma unroll
    for (int kc = 0; kc < 4; ++kc)
        qf[kc] = *reinterpret_cast<const s16x8*>(Qb + (size_t)qrow * 128 + kc * 32 + hi * 8);

    float m_run = -1e30f, l_run = 0.f;                  // exp2-domain; lane's q-row = lo
    f32x4 o[8];
#pragma unroll
    for (int n = 0; n < 8; ++n) o[n] = f32x4{0.f, 0.f, 0.f, 0.f};
    const float scale2 = 0.12751682f;                   // 1/sqrt(128) * log2(e)

    // --- staging geometry ---
    const int krow = tid >> 4, kc8 = tid & 15;          // krow 0..31 (+i*32)
    const int koff = (kc8 ^ (krow & 7)) * 8;
    const int vrow = tid >> 3, vc8 = tid & 7;           // vrow 0..63 (+i*64)
    const int voff = (vc8 ^ (vrow & 7)) * 8;

    s16x8 kreg[2], vreg[2];
    auto load_tile = [&](int kv0) {
#pragma unroll
        for (int i = 0; i < 2; ++i)
            kreg[i] = *reinterpret_cast<const s16x8*>(
                Kb + (size_t)(kv0 + i * 32 + krow) * 128 + kc8 * 8);
#pragma unroll
        for (int i = 0; i < 2; ++i)
            vreg[i] = *reinterpret_cast<const s16x8*>(
                Vb + (size_t)(i * 64 + vrow) * S + kv0 + vc8 * 8);
    };

    auto body = [&](int kt, __hip_bfloat16* Kc, __hip_bfloat16* Vc) {
        const int kv0 = kt * 64;
#pragma unroll
        for (int i = 0; i < 2; ++i)
            *reinterpret_cast<s16x8*>(Kc + (i * 32 + krow) * 128 + koff) = kreg[i];
#pragma unroll
        for (int i = 0; i < 2; ++i)
            *reinterpret_cast<s16x8*>(Vc + (i * 64 + vrow) * 64 + voff) = vreg[i];
        if (kt < 31) load_tile(kv0 + 64);               // lands under compute (T14)
        f32x4 bi[4];
#pragma unroll
        for (int ksub = 0; ksub < 4; ++ksub)
            bi[ksub] = *reinterpret_cast<const f32x4*>(mrow + kv0 + ksub * 16 + hi * 4);
        __syncthreads();                                // buf ready for all

        // P^T = (K Q^T): lane holds P[kv=ksub*16+hi*4+r][q=lo]
        f32x4 sc[4] = {};
        __builtin_amdgcn_s_setprio(1);
#pragma unroll
        for (int ksub = 0; ksub < 4; ++ksub) {
            const int kr = ksub * 16 + lo;
            const int ksw = kr & 7;
#pragma unroll
            for (int kc = 0; kc < 4; ++kc) {
                s16x8 kf = *reinterpret_cast<const s16x8*>(
                    Kc + kr * 128 + (((kc * 4 + hi) ^ ksw) * 8));
                sc[ksub] = __builtin_amdgcn_mfma_f32_16x16x32_bf16(kf, qf[kc], sc[ksub], 0, 0, 0);
            }
        }
        __builtin_amdgcn_s_setprio(0);
        // scale (log2-domain) + additive mask bias
#pragma unroll
        for (int ksub = 0; ksub < 4; ++ksub)
#pragma unroll
            for (int r = 0; r < 4; ++r)
                sc[ksub][r] = fmaf(sc[ksub][r], scale2, bi[ksub][r]);
        // tile row-max
        float a0 = fmaxf(fmaxf(sc[0][0], sc[0][1]), fmaxf(sc[0][2], sc[0][3]));
        float a1 = fmaxf(fmaxf(sc[1][0], sc[1][1]), fmaxf(sc[1][2], sc[1][3]));
        float a2 = fmaxf(fmaxf(sc[2][0], sc[2][1]), fmaxf(sc[2][2], sc[2][3]));
        float a3 = fmaxf(fmaxf(sc[3][0], sc[3][1]), fmaxf(sc[3][2], sc[3][3]));
        float mx = fmaxf(fmaxf(a0, a1), fmaxf(a2, a3));
        mx = fmaxf(mx, __shfl_xor(mx, 16));
        mx = fmaxf(mx, __shfl_xor(mx, 32));
        // defer-max: only rescale when some row's max grew past 8*log2e
        if (__ballot(mx > m_run + 11.5417f) != 0ull) {
            const float mnew = fmaxf(m_run, mx);
            const float alpha = fexp2(m_run - mnew);
            m_run = mnew;
            l_run *= alpha;
            float ar[4];
#pragma unroll
            for (int r = 0; r < 4; ++r) ar[r] = __shfl(alpha, hi * 4 + r);
#pragma unroll
            for (int n = 0; n < 8; ++n)
#pragma unroll
                for (int r = 0; r < 4; ++r) o[n][r] *= ar[r];
        }
        // exp2 + row-sum (P bounded by 2^11.54 = e^8 under defer)
        float s0 = 0.f, s1 = 0.f, s2 = 0.f, s3 = 0.f;
#pragma unroll
        for (int r = 0; r < 4; ++r) {
            sc[0][r] = fexp2(sc[0][r] - m_run); s0 += sc[0][r];
            sc[1][r] = fexp2(sc[1][r] - m_run); s1 += sc[1][r];
            sc[2][r] = fexp2(sc[2][r] - m_run); s2 += sc[2][r];
            sc[3][r] = fexp2(sc[3][r] - m_run); s3 += sc[3][r];
        }
        float ssum = (s0 + s1) + (s2 + s3);
        ssum += __shfl_xor(ssum, 16);
        ssum += __shfl_xor(ssum, 32);
        l_run += ssum;
        // P -> LDS: cvt_pk pairs, one b64 per ksub (row q=lo, cols ksub*16+hi*4..+3)
        __hip_bfloat16* pb = &Ps[w][0];
#pragma unroll
        for (int ksub = 0; ksub < 4; ++ksub) {
            unsigned int d0, d1;
            asm("v_cvt_pk_bf16_f32 %0, %1, %2" : "=v"(d0) : "v"(sc[ksub][0]), "v"(sc[ksub][1]));
            asm("v_cvt_pk_bf16_f32 %0, %1, %2" : "=v"(d1) : "v"(sc[ksub][2]), "v"(sc[ksub][3]));
            const int byteoff = lo * 128 + (((ksub * 2 + (hi >> 1)) ^ (lo & 7)) * 16) + (hi & 1) * 8;
            uint2 dd; dd.x = d0; dd.y = d1;
            *reinterpret_cast<uint2*>(reinterpret_cast<char*>(pb) + byteoff) = dd;
        }
        // O += P V
        __builtin_amdgcn_s_setprio(1);
#pragma unroll
        for (int kg = 0; kg < 2; ++kg) {
            s16x8 pa = *reinterpret_cast<const s16x8*>(
                pb + lo * 64 + (((kg * 4 + hi) ^ (lo & 7)) * 8));
#pragma unroll
            for (int n = 0; n < 8; ++n) {
                const int vr = n * 16 + lo;
                s16x8 vb = *reinterpret_cast<const s16x8*>(
                    Vc + vr * 64 + (((kg * 4 + hi) ^ (vr & 7)) * 8));
                o[n] = __builtin_amdgcn_mfma_f32_16x16x32_bf16(pa, vb, o[n], 0, 0, 0);
            }
        }
        __builtin_amdgcn_s_setprio(0);
        // no trailing barrier: next call writes the other buffer
    };

    load_tile(0);
    for (int kt2 = 0; kt2 < 16; ++kt2) {                // x2 unroll: static LDS bases
        body(2 * kt2,     &Ks[0][0], &Vs[0][0]);
        body(2 * kt2 + 1, &Ks[1][0], &Vs[1][0]);
    }
    // epilogue: attn_out[b*S+s][h*128+d] = o / l   (l lives at lane q)
    float lr[4];
#pragma unroll
    for (int r = 0; r < 4; ++r) lr[r] = __shfl(l_run, hi * 4 + r);
    const int orow = b * S + qt * 128 + w * 16 + (hi * 4);
    const int ocol = h * 128 + lo;
#pragma unroll
    for (int n = 0; n < 8; ++n)
#pragma unroll
        for (int r = 0; r < 4; ++r)
            Oo[(size_t)(orow + r) * 2048 + ocol + n * 16] = __float2bfloat16(o[n][r] / lr[r]);
}

// ---------------- host launch ----------------
extern "C" void kernel_launch(void* const* d_in, const int* in_sizes, int n_in,
                              void* d_out, int out_size, void* d_ws, size_t ws_size,
                              hipStream_t stream) {
    const float* x  = (const float*)d_in[0];
    const int* mask = (const int*)d_in[1];
    const float* Wq = (const float*)d_in[2];
    const float* Wk = (const float*)d_in[3];
    const float* Wv = (const float*)d_in[4];
    const float* Wo = (const float*)d_in[5];
    float* out = (float*)d_out;

    char* ws = (char*)d_ws;
    size_t off = 0;
    auto alloc = [&](size_t bytes) -> void* {
        void* p = ws + off;
        off += (bytes + 255) & ~(size_t)255;
        return p;
    };
    __hip_bfloat16* xb     = (__hip_bfloat16*)alloc(4096ULL * 2048 * 2);   // 16 MB
    __hip_bfloat16* wqkv_t = (__hip_bfloat16*)alloc(3072ULL * 2048 * 2);   // 12 MB
    __hip_bfloat16* wo_t   = (__hip_bfloat16*)alloc(2048ULL * 2048 * 2);   // 8 MB
    float*          qkv    = (float*)alloc(4096ULL * 3072 * 4);            // 48 MB
    __hip_bfloat16* Kr     = (__hip_bfloat16*)alloc(2ULL * 4 * 2048 * 128 * 2);  // 4 MB
    __hip_bfloat16* Vt     = (__hip_bfloat16*)alloc(2ULL * 4 * 2048 * 128 * 2);  // 4 MB
    float*          cosT   = (float*)alloc(2048ULL * 64 * 4);
    float*          sinT   = (float*)alloc(2048ULL * 64 * 4);
    float*          maskb  = (float*)alloc(2ULL * 2048 * 4);
    // Aliases (regions dead by the time these are written):
    __hip_bfloat16* Qr    = xb;                   // xb dead after QKV GEMM; Qr written after
    __hip_bfloat16* attno = (__hip_bfloat16*)qkv; // qkv dead after rope/vt; attno written after

    rope_tables<<<dim3(2048), dim3(64), 0, stream>>>(cosT, sinT);
    mask_bias<<<dim3(16), dim3(256), 0, stream>>>(mask, maskb, 4096);
    cast_f32_bf16<<<dim3(8192), dim3(256), 0, stream>>>(x, xb, 2097152);
    transpose_cast<<<dim3(64, 64), dim3(32, 8), 0, stream>>>(Wq, wqkv_t, 2048, 2048);
    transpose_cast<<<dim3(16, 64), dim3(32, 8), 0, stream>>>(Wk, wqkv_t + 2048ULL * 2048, 2048, 512);
    transpose_cast<<<dim3(16, 64), dim3(32, 8), 0, stream>>>(Wv, wqkv_t + 2560ULL * 2048, 2048, 512);
    transpose_cast<<<dim3(64, 64), dim3(32, 8), 0, stream>>>(Wo, wo_t, 2048, 2048);

    // QKV: 256x256 tiles -> grid (12,16)
    gemm256_bt_f32<4><<<dim3(12, 16), dim3(512), 0, stream>>>(xb, wqkv_t, qkv, 4096, 3072, 2048);
    rope_scatter<<<dim3(3, 4096), dim3(256), 0, stream>>>(qkv, cosT, sinT, Qr, Kr);
    vt_transpose<<<dim3(64, 4, 8), dim3(32, 8), 0, stream>>>(qkv, Vt);
    attn_kernel<<<dim3(16, 32), dim3(512), 0, stream>>>(Qr, Kr, Vt, maskb, attno);
    // Wo: 256x128 tiles -> grid (16,16) = 256 blocks (full chip)
    gemm256_bt_f32<2><<<dim3(16, 16), dim3(512), 0, stream>>>(attno, wo_t, out, 4096, 2048, 2048);
}